// Round 11
// baseline (322.296 us; speedup 1.0000x reference)
//
#include <hip/hip_runtime.h>
#include <hip/hip_cooperative_groups.h>
#include <cstddef>

namespace cg = cooperative_groups;

#define BB    16
#define NN    2048
#define BN    (BB * NN)
#define EPSF  1e-9f
#define TPB   512
#define CPT   2                 // columns (rows) per thread
#define CHUNK 1024              // TPB*CPT columns per block-half
#define K9C   4                 // k9: 512 threads x 4 = 2048
// mega geometry (R2-proven): 16 splits x 2 col-chunks x 16 batches = 512 blocks
#define MTILE 128
#define MGRID 512
// fallback geometry (R9-proven): 32 splits x 2 col-chunks x 16 batches = 1024
#define FTILE 64
#define FGRID 1024

// OCML native exp2 is always linkable; builtin preferred (both -> v_exp_f32).
extern "C" __device__ float __ocml_native_exp2_f32(float);
__device__ __forceinline__ float fast_exp2(float x) {
#if __has_builtin(__builtin_amdgcn_exp2f)
    return __builtin_amdgcn_exp2f(x);
#else
    return __ocml_native_exp2_f32(x);
#endif
}

__device__ __forceinline__ float block_sum(float v, int t, float* tmp8) {
#pragma unroll
    for (int o = 32; o > 0; o >>= 1) v += __shfl_down(v, o, 64);
    __syncthreads();                       // protect tmp8 reuse across calls
    if ((t & 63) == 0) tmp8[t >> 6] = v;
    __syncthreads();
    float s = 0.0f;
#pragma unroll
    for (int w = 0; w < TPB / 64; w++) s += tmp8[w];
    return s;
}

// Release-fence, grid barrier, acquire-fence: in-kernel replacement for the
// kernel-boundary cache flush (cross-XCD L2 coherence on plain loads/stores).
__device__ __forceinline__ void gsync(cg::grid_group& g) {
    __threadfence();
    g.sync();
    __threadfence();
}

__device__ const float d_efs[9] = {-16384.0f, -4096.0f, -1024.0f, -256.0f,
                                   -64.0f, -16.0f, -4.0f, -1.0f, -0.25f};

// ===================== mega: 9 rounds x {A,B} + k9 tail ======================
// Phase bodies = proven scalar pattern (R0/R9), R2 geometry. 512 blocks =
// 2 blocks/CU (co-residency safe at <=128 VGPR via launch_bounds(512,4)).
__global__ __launch_bounds__(TPB, 4) void mega(
    const float* __restrict__ preds, const float* __restrict__ labels,
    float* __restrict__ out, float* __restrict__ ws)
{
    cg::grid_group grid = cg::this_grid();
    __shared__ float4 s_p[MTILE];   // A: (px,py,pz, c1*|p|^2)
    __shared__ float  s_cu[MTILE];
    __shared__ float  s_red[2];
    __shared__ float4 s_l[MTILE];   // B: (-2c1*lx,-2c1*ly,-2c1*lz, c1*|l|^2)
    __shared__ float  s_cc[MTILE];
    __shared__ float  tmp8[TPB / 64];

    int blk = blockIdx.x;
    int split = blk & 15, mc = (blk >> 4) & 1, b = blk >> 5;
    int t = threadIdx.x;
    int base = b * NN;

    // init: zero S[0],T[0] (first 2*BN floats) and out (replay-correct)
    {
        int gid = blk * TPB + t;
        if (gid < 2 * BN) ws[gid] = 0.0f;
        if (gid == 0) *out = 0.0f;
    }
    gsync(grid);

    const float log2e = 1.44269504088896f;
    for (int k = 0; k < 9; k++) {
        float c1 = d_efs[k] * log2e;
        float invc1 = 1.0f / c1;
        int pk = k & 1, pp = pk ^ 1;
        float* Sk    = ws + (size_t)(2 * pk) * BN;
        float* Tk    = ws + (size_t)(2 * pk + 1) * BN;
        float* Sp    = ws + (size_t)(2 * pp) * BN;
        float* Tp    = ws + (size_t)(2 * pp + 1) * BN;
        float* RSk   = ws + (size_t)(4 + 2 * pk) * BN;
        float* RRk   = ws + (size_t)(5 + 2 * pk) * BN;
        float* RSp   = ws + (size_t)(4 + 2 * pp) * BN;
        float* RRp   = ws + (size_t)(5 + 2 * pp) * BN;
        float* curk  = ws + (size_t)(8 + pk) * BN;
        float* curp  = ws + (size_t)(8 + pp) * BN;
        float* costk = ws + (size_t)(10 + pk) * BN;
        float* costp = ws + (size_t)(10 + pp) * BN;

        // ===== phase A =====
        if (t < MTILE) {                       // waves 0,1
            int idx = base + split * MTILE + t;
            const float* p = preds + (size_t)idx * 3;
            float px = p[0], py = p[1], pz = p[2];
            float pn = px * px + py * py + pz * pz;
            float cu, contrib = 0.0f;
            if (k == 0) cu = 1.0f;
            else {
                float cup = curp[idx], rs = RSp[idx], rr = RRp[idx];
                contrib = cup * rr;                       // round k-1 result term
                cu = fmaxf(cup * (1.0f - rs), 0.0f);
            }
            s_p[t]  = make_float4(px, py, pz, c1 * pn);
            s_cu[t] = cu;
            if (mc == 0) {
                curk[idx] = cu;
                RSk[idx] = 0.0f; RRk[idx] = 0.0f;         // for this round's B
            }
            if (k > 0 && mc == 0) {
#pragma unroll
                for (int o = 32; o > 0; o >>= 1) contrib += __shfl_down(contrib, o, 64);
                if ((t & 63) == 0) s_red[t >> 6] = contrib;
            }
        }
        {
            int m0 = mc * CHUNK + t;
            float gx[CPT], gy[CPT], gz[CPT], am[CPT], Sa[CPT], Ta[CPT];
            float n2c1 = -2.0f * c1;
#pragma unroll
            for (int c = 0; c < CPT; c++) {
                int m = m0 + c * TPB;
                const float* l = labels + (size_t)(base + m) * 3;
                float lx = l[0], ly = l[1], lz = l[2];
                gx[c] = n2c1 * lx; gy[c] = n2c1 * ly; gz[c] = n2c1 * lz;
                am[c] = c1 * (lx * lx + ly * ly + lz * lz);
                Sa[c] = 0.0f; Ta[c] = 0.0f;
            }
            __syncthreads();
            if (k > 0 && mc == 0 && t == 0) atomicAdd(out, s_red[0] + s_red[1]);

#pragma unroll 4
            for (int j = 0; j < MTILE; j++) {
                float4 P = s_p[j]; float cu = s_cu[j];
#pragma unroll
                for (int c = 0; c < CPT; c++) {
                    float arg = fmaf(P.x, gx[c], fmaf(P.y, gy[c], fmaf(P.z, gz[c], P.w + am[c])));
                    float e = fast_exp2(arg);
                    Sa[c] += e;
                    Ta[c] = fmaf(e, cu, Ta[c]);
                }
            }
#pragma unroll
            for (int c = 0; c < CPT; c++) {
                int idx = base + m0 + c * TPB;
                atomicAdd(&Sk[idx], Sa[c]);
                atomicAdd(&Tk[idx], Ta[c]);
            }
        }
        gsync(grid);

        // ===== phase B =====
        if (t < MTILE) {
            int idx = base + split * MTILE + t;
            const float* l = labels + (size_t)idx * 3;
            float lx = l[0], ly = l[1], lz = l[2];
            float lm2 = lx * lx + ly * ly + lz * lz;
            float S = Sk[idx], T = Tk[idx];
            float cost = (k == 0) ? 1.0f : costk[idx];
            float D1 = fmaf(cost, S, EPSF);
            float S2 = cost * T / D1;
            float bw = fminf(cost / (S2 + EPSF), 1.0f);
            float cc = cost * bw / D1;
            float n2c1 = -2.0f * c1;
            s_l[t]  = make_float4(n2c1 * lx, n2c1 * ly, n2c1 * lz, c1 * lm2);
            s_cc[t] = cc;
            if (mc == 0) {
                costp[idx] = fmaxf(fmaf(-S2, bw, cost), 0.0f);
                Sp[idx] = 0.0f; Tp[idx] = 0.0f;           // for next round's A
            }
        }
        {
            int n0 = mc * CHUNK + t;
            float px[CPT], py[CPT], pz[CPT], qq[CPT], RSa[CPT], RRa[CPT];
#pragma unroll
            for (int c = 0; c < CPT; c++) {
                int n = n0 + c * TPB;
                const float* p = preds + (size_t)(base + n) * 3;
                px[c] = p[0]; py[c] = p[1]; pz[c] = p[2];
                qq[c] = c1 * (px[c] * px[c] + py[c] * py[c] + pz[c] * pz[c]);
                RSa[c] = 0.0f; RRa[c] = 0.0f;
            }
            __syncthreads();

#pragma unroll 4
            for (int j = 0; j < MTILE; j++) {
                float4 L = s_l[j]; float ccj = s_cc[j];
#pragma unroll
                for (int c = 0; c < CPT; c++) {
                    float arg = fmaf(px[c], L.x, fmaf(py[c], L.y, fmaf(pz[c], L.z, qq[c] + L.w)));
                    float e = fast_exp2(arg);
                    float w = e * ccj;
                    RSa[c] += w;
                    RRa[c] = fmaf(w, arg, RRa[c]);        // sum w*arg; *1/c1 at end
                }
            }
#pragma unroll
            for (int c = 0; c < CPT; c++) {
                int idx = base + n0 + c * TPB;
                atomicAdd(&RSk[idx], RSa[c]);
                atomicAdd(&RRk[idx], RRa[c] * invc1);
            }
        }
        gsync(grid);
    }

    // ===== k9 tail (round 9, ef=0): algebraic collapse; blocks 0..15 =====
    if (blk < BB) {
        const float* cur8  = ws + (size_t)8 * BN;    // curb[0]
        const float* RS8   = ws + (size_t)4 * BN;    // RS[0]
        const float* RR8   = ws + (size_t)5 * BN;    // RR[0]
        const float* cost9 = ws + (size_t)11 * BN;   // costb[1]
        int kbase = blk * NN;

        float cu9[K9C];
        float contrib = 0.0f, csum = 0.0f;
#pragma unroll
        for (int c = 0; c < K9C; c++) {
            int idx = kbase + t + c * TPB;
            float cup = cur8[idx];
            contrib = fmaf(cup, RR8[idx], contrib);       // round-8 result term
            float cu = fmaxf(cup * (1.0f - RS8[idx]), 0.0f);
            cu9[c] = cu; csum += cu;
        }
        float contribT = block_sum(contrib, t, tmp8);
        float Cb = block_sum(csum, t, tmp8);              // T[m] == Cb for all m

        float A = 0.0f, Bs = 0.0f, Vx = 0.0f, Vy = 0.0f, Vz = 0.0f;
#pragma unroll
        for (int c = 0; c < K9C; c++) {
            int idx = kbase + t + c * TPB;
            const float* l = labels + (size_t)idx * 3;
            float lx = l[0], ly = l[1], lz = l[2];
            float cost = cost9[idx];
            float D1 = fmaf(cost, 2048.0f, EPSF);         // S == 2048 exactly
            float S2 = cost * Cb / D1;
            float bw = fminf(cost / (S2 + EPSF), 1.0f);
            float cc = cost * bw / D1;
            A += cc;
            Bs = fmaf(cc, lx * lx + ly * ly + lz * lz, Bs);
            Vx = fmaf(cc, lx, Vx); Vy = fmaf(cc, ly, Vy); Vz = fmaf(cc, lz, Vz);
        }
        float At  = block_sum(A, t, tmp8);
        float Bt  = block_sum(Bs, t, tmp8);
        float Vxt = block_sum(Vx, t, tmp8);
        float Vyt = block_sum(Vy, t, tmp8);
        float Vzt = block_sum(Vz, t, tmp8);

        float acc = 0.0f;
#pragma unroll
        for (int c = 0; c < K9C; c++) {
            int idx = kbase + t + c * TPB;
            const float* p = preds + (size_t)idx * 3;
            float x = p[0], y = p[1], z = p[2];
            float pn = x * x + y * y + z * z;
            float rr = fmaf(At, pn, Bt) - 2.0f * (x * Vxt + y * Vyt + z * Vzt);
            acc = fmaf(cu9[c], rr, acc);                  // round-9 result term
        }
        float accT = block_sum(acc, t, tmp8);
        if (t == 0) atomicAdd(out, contribT + accT);
    }
}

// ===================== fallback: R9 multi-kernel (proven PASS) ===============
__global__ __launch_bounds__(TPB, 8) void passAf(
    const float* __restrict__ preds, const float* __restrict__ labels,
    const float* __restrict__ curprev, float* __restrict__ curout,
    const float* __restrict__ RSprev, const float* __restrict__ RRprev,
    float* __restrict__ RSz, float* __restrict__ RRz,
    float* __restrict__ Sacc, float* __restrict__ Tacc,
    float* __restrict__ out, float c1, int k)
{
    __shared__ float4 s_p[FTILE];
    __shared__ float  s_cu[FTILE];
    __shared__ float  s_red0;
    int blk = blockIdx.x;
    int split = blk & 31, mc = (blk >> 5) & 1, b = blk >> 6;
    int t = threadIdx.x;
    int base = b * NN;

    if (t < FTILE) {
        int idx = base + split * FTILE + t;
        const float* p = preds + (size_t)idx * 3;
        float px = p[0], py = p[1], pz = p[2];
        float pn = px * px + py * py + pz * pz;
        float cu, contrib = 0.0f;
        if (k == 0) cu = 1.0f;
        else {
            float cup = curprev[idx], rs = RSprev[idx], rr = RRprev[idx];
            contrib = cup * rr;
            cu = fmaxf(cup * (1.0f - rs), 0.0f);
        }
        s_p[t]  = make_float4(px, py, pz, c1 * pn);
        s_cu[t] = cu;
        if (mc == 0) {
            curout[idx] = cu;
            RSz[idx] = 0.0f; RRz[idx] = 0.0f;
        }
        if (k > 0) {
#pragma unroll
            for (int o = 32; o > 0; o >>= 1) contrib += __shfl_down(contrib, o, 64);
            if (t == 0) s_red0 = contrib;
        }
    }
    int m0 = mc * CHUNK + t;
    float gx[CPT], gy[CPT], gz[CPT], am[CPT], Sa[CPT], Ta[CPT];
    float n2c1 = -2.0f * c1;
#pragma unroll
    for (int c = 0; c < CPT; c++) {
        int m = m0 + c * TPB;
        const float* l = labels + (size_t)(base + m) * 3;
        float lx = l[0], ly = l[1], lz = l[2];
        gx[c] = n2c1 * lx; gy[c] = n2c1 * ly; gz[c] = n2c1 * lz;
        am[c] = c1 * (lx * lx + ly * ly + lz * lz);
        Sa[c] = 0.0f; Ta[c] = 0.0f;
    }
    __syncthreads();
    if (k > 0 && mc == 0 && t == 0) atomicAdd(out, s_red0);

#pragma unroll 4
    for (int j = 0; j < FTILE; j++) {
        float4 P = s_p[j]; float cu = s_cu[j];
#pragma unroll
        for (int c = 0; c < CPT; c++) {
            float arg = fmaf(P.x, gx[c], fmaf(P.y, gy[c], fmaf(P.z, gz[c], P.w + am[c])));
            float e = fast_exp2(arg);
            Sa[c] += e;
            Ta[c] = fmaf(e, cu, Ta[c]);
        }
    }
#pragma unroll
    for (int c = 0; c < CPT; c++) {
        int idx = base + m0 + c * TPB;
        atomicAdd(&Sacc[idx], Sa[c]);
        atomicAdd(&Tacc[idx], Ta[c]);
    }
}

__global__ __launch_bounds__(TPB, 8) void passBf(
    const float* __restrict__ preds, const float* __restrict__ labels,
    const float* __restrict__ Sread, const float* __restrict__ Tread,
    const float* __restrict__ costprev, float* __restrict__ costout,
    float* __restrict__ Sz, float* __restrict__ Tz,
    float* __restrict__ RSacc, float* __restrict__ RRacc,
    float c1, float invc1, int k)
{
    __shared__ float4 s_l[FTILE];
    __shared__ float  s_cc[FTILE];
    int blk = blockIdx.x;
    int split = blk & 31, nc = (blk >> 5) & 1, b = blk >> 6;
    int t = threadIdx.x;
    int base = b * NN;

    if (t < FTILE) {
        int idx = base + split * FTILE + t;
        const float* l = labels + (size_t)idx * 3;
        float lx = l[0], ly = l[1], lz = l[2];
        float lm2 = lx * lx + ly * ly + lz * lz;
        float S = Sread[idx], T = Tread[idx];
        float cost = (k == 0) ? 1.0f : costprev[idx];
        float D1 = fmaf(cost, S, EPSF);
        float S2 = cost * T / D1;
        float bw = fminf(cost / (S2 + EPSF), 1.0f);
        float cc = cost * bw / D1;
        float n2c1 = -2.0f * c1;
        s_l[t]  = make_float4(n2c1 * lx, n2c1 * ly, n2c1 * lz, c1 * lm2);
        s_cc[t] = cc;
        if (nc == 0) {
            costout[idx] = fmaxf(fmaf(-S2, bw, cost), 0.0f);
            Sz[idx] = 0.0f; Tz[idx] = 0.0f;
        }
    }
    int n0 = nc * CHUNK + t;
    float px[CPT], py[CPT], pz[CPT], qq[CPT], RSa[CPT], RRa[CPT];
#pragma unroll
    for (int c = 0; c < CPT; c++) {
        int n = n0 + c * TPB;
        const float* p = preds + (size_t)(base + n) * 3;
        px[c] = p[0]; py[c] = p[1]; pz[c] = p[2];
        qq[c] = c1 * (px[c] * px[c] + py[c] * py[c] + pz[c] * pz[c]);
        RSa[c] = 0.0f; RRa[c] = 0.0f;
    }
    __syncthreads();

#pragma unroll 4
    for (int j = 0; j < FTILE; j++) {
        float4 L = s_l[j]; float ccj = s_cc[j];
#pragma unroll
        for (int c = 0; c < CPT; c++) {
            float arg = fmaf(px[c], L.x, fmaf(py[c], L.y, fmaf(pz[c], L.z, qq[c] + L.w)));
            float e = fast_exp2(arg);
            float w = e * ccj;
            RSa[c] += w;
            RRa[c] = fmaf(w, arg, RRa[c]);
        }
    }
#pragma unroll
    for (int c = 0; c < CPT; c++) {
        int idx = base + n0 + c * TPB;
        atomicAdd(&RSacc[idx], RSa[c]);
        atomicAdd(&RRacc[idx], RRa[c] * invc1);
    }
}

__global__ __launch_bounds__(TPB, 1) void k9f(
    const float* __restrict__ preds, const float* __restrict__ labels,
    const float* __restrict__ cur8, const float* __restrict__ RS8,
    const float* __restrict__ RR8, const float* __restrict__ cost9,
    float* __restrict__ out)
{
    __shared__ float tmp8[TPB / 64];
    int b = blockIdx.x, t = threadIdx.x;
    int base = b * NN;

    float cu9[K9C];
    float contrib = 0.0f, csum = 0.0f;
#pragma unroll
    for (int c = 0; c < K9C; c++) {
        int idx = base + t + c * TPB;
        float cup = cur8[idx];
        contrib = fmaf(cup, RR8[idx], contrib);
        float cu = fmaxf(cup * (1.0f - RS8[idx]), 0.0f);
        cu9[c] = cu; csum += cu;
    }
    float contribT = block_sum(contrib, t, tmp8);
    float Cb = block_sum(csum, t, tmp8);

    float A = 0.0f, Bs = 0.0f, Vx = 0.0f, Vy = 0.0f, Vz = 0.0f;
#pragma unroll
    for (int c = 0; c < K9C; c++) {
        int idx = base + t + c * TPB;
        const float* l = labels + (size_t)idx * 3;
        float lx = l[0], ly = l[1], lz = l[2];
        float cost = cost9[idx];
        float D1 = fmaf(cost, 2048.0f, EPSF);
        float S2 = cost * Cb / D1;
        float bw = fminf(cost / (S2 + EPSF), 1.0f);
        float cc = cost * bw / D1;
        A += cc;
        Bs = fmaf(cc, lx * lx + ly * ly + lz * lz, Bs);
        Vx = fmaf(cc, lx, Vx); Vy = fmaf(cc, ly, Vy); Vz = fmaf(cc, lz, Vz);
    }
    float At  = block_sum(A, t, tmp8);
    float Bt  = block_sum(Bs, t, tmp8);
    float Vxt = block_sum(Vx, t, tmp8);
    float Vyt = block_sum(Vy, t, tmp8);
    float Vzt = block_sum(Vz, t, tmp8);

    float acc = 0.0f;
#pragma unroll
    for (int c = 0; c < K9C; c++) {
        int idx = base + t + c * TPB;
        const float* p = preds + (size_t)idx * 3;
        float x = p[0], y = p[1], z = p[2];
        float pn = x * x + y * y + z * z;
        float rr = fmaf(At, pn, Bt) - 2.0f * (x * Vxt + y * Vyt + z * Vzt);
        acc = fmaf(cu9[c], rr, acc);
    }
    float accT = block_sum(acc, t, tmp8);
    if (t == 0) atomicAdd(out, contribT + accT);
}

extern "C" void kernel_launch(void* const* d_in, const int* in_sizes, int n_in,
                              void* d_out, int out_size, void* d_ws, size_t ws_size,
                              hipStream_t stream) {
    const float* preds  = (const float*)d_in[0];
    const float* labels = (const float*)d_in[1];
    float* out = (float*)d_out;
    float* ws  = (float*)d_ws;

    // Decide coop feasibility (deterministic per process -> same work per call).
    int nb = 0;
    hipError_t qrc = hipOccupancyMaxActiveBlocksPerMultiprocessor(
        &nb, (const void*)mega, TPB, 0);
    bool coop = (qrc == hipSuccess) && (nb * 256 >= MGRID);
    if (coop) {
        void* args[4] = {(void*)&preds, (void*)&labels, (void*)&out, (void*)&ws};
        hipError_t rc = hipLaunchCooperativeKernel((const void*)mega, dim3(MGRID),
                                                   dim3(TPB), args, 0, stream);
        if (rc != hipSuccess) coop = false;
    }
    if (!coop) {
        // R9-proven multi-kernel path
        float* S[2]     = {ws + 0 * BN, ws + 2 * BN};
        float* T[2]     = {ws + 1 * BN, ws + 3 * BN};
        float* RS[2]    = {ws + 4 * BN, ws + 6 * BN};
        float* RR[2]    = {ws + 5 * BN, ws + 7 * BN};
        float* curb[2]  = {ws + 8 * BN, ws + 9 * BN};
        float* costb[2] = {ws + 10 * BN, ws + 11 * BN};

        hipMemsetAsync(d_out, 0, sizeof(float), stream);
        hipMemsetAsync(ws, 0, (size_t)2 * BN * sizeof(float), stream);

        static const float efs[9] = {-16384.0f, -4096.0f, -1024.0f, -256.0f,
                                     -64.0f, -16.0f, -4.0f, -1.0f, -0.25f};
        const float log2e = 1.44269504088896f;
        for (int k = 0; k < 9; k++) {
            float c1 = efs[k] * log2e;
            float invc1 = 1.0f / c1;
            int pk = k & 1, pp = (k + 1) & 1;
            passAf<<<FGRID, TPB, 0, stream>>>(preds, labels,
                curb[pp], curb[pk], RS[pp], RR[pp], RS[pk], RR[pk],
                S[pk], T[pk], out, c1, k);
            passBf<<<FGRID, TPB, 0, stream>>>(preds, labels,
                S[pk], T[pk], costb[pk], costb[pp], S[pp], T[pp],
                RS[pk], RR[pk], c1, invc1, k);
        }
        k9f<<<BB, TPB, 0, stream>>>(preds, labels, curb[0], RS[0], RR[0],
                                    costb[1], out);
    }
}

// Round 12
// 320.931 us; speedup vs baseline: 1.0043x; 1.0043x over previous
//
#include <hip/hip_runtime.h>
#include <hip/hip_cooperative_groups.h>
#include <cstddef>

namespace cg = cooperative_groups;

#define BB    16
#define NN    2048
#define BN    (BB * NN)
#define EPSF  1e-9f
#define TPB   512
#define CPT   2                 // columns (rows) per thread
#define CHUNK 1024              // TPB*CPT columns per block-half
#define K9C   4                 // k9: 512 threads x 4 = 2048
// mega geometry (R9-proven): 32 splits x 2 col-chunks x 16 batches = 1024 blocks
#define TILE  64
#define MGRID 1024

// OCML native exp2 is always linkable; builtin preferred (both -> v_exp_f32).
extern "C" __device__ float __ocml_native_exp2_f32(float);
__device__ __forceinline__ float fast_exp2(float x) {
#if __has_builtin(__builtin_amdgcn_exp2f)
    return __builtin_amdgcn_exp2f(x);
#else
    return __ocml_native_exp2_f32(x);
#endif
}

__device__ __forceinline__ float block_sum(float v, int t, float* tmp8) {
#pragma unroll
    for (int o = 32; o > 0; o >>= 1) v += __shfl_down(v, o, 64);
    __syncthreads();                       // protect tmp8 reuse across calls
    if ((t & 63) == 0) tmp8[t >> 6] = v;
    __syncthreads();
    float s = 0.0f;
#pragma unroll
    for (int w = 0; w < TPB / 64; w++) s += tmp8[w];
    return s;
}

// Release-fence, grid barrier, acquire-fence: in-kernel replacement for the
// kernel-boundary cache flush (cross-XCD L2 coherence on plain loads/stores).
__device__ __forceinline__ void gsync(cg::grid_group& g) {
    __threadfence();
    g.sync();
    __threadfence();
}

__device__ const float d_efs[9] = {-16384.0f, -4096.0f, -1024.0f, -256.0f,
                                   -64.0f, -16.0f, -4.0f, -1.0f, -0.25f};

// ============ mega: 9 rounds x {A,B} + k9 tail, 1024 blocks coop ============
// Bodies = R9's passA/passB verbatim (PASS, absmax 0.0, bounds(512,8), VGPR~40).
// 1024 blocks = 4 blocks/CU = 32 waves/CU co-resident.
__global__ __launch_bounds__(TPB, 8) void mega(
    const float* __restrict__ preds, const float* __restrict__ labels,
    float* __restrict__ out, float* __restrict__ ws)
{
    cg::grid_group grid = cg::this_grid();
    __shared__ float4 s_p[TILE];    // A: (px,py,pz, c1*|p|^2)
    __shared__ float  s_cu[TILE];
    __shared__ float  s_red0;
    __shared__ float4 s_l[TILE];    // B: (-2c1*lx,-2c1*ly,-2c1*lz, c1*|l|^2)
    __shared__ float  s_cc[TILE];
    __shared__ float  tmp8[TPB / 64];

    int blk = blockIdx.x;
    int split = blk & 31, mc = (blk >> 5) & 1, b = blk >> 6;
    int t = threadIdx.x;
    int base = b * NN;

    // init: zero S[0],T[0] (first 2*BN floats) and out (replay-correct)
    {
        int gid = blk * TPB + t;
        if (gid < 2 * BN) ws[gid] = 0.0f;
        if (gid == 0) *out = 0.0f;
    }
    gsync(grid);

    const float log2e = 1.44269504088896f;
    for (int k = 0; k < 9; k++) {
        float c1 = d_efs[k] * log2e;
        float invc1 = 1.0f / c1;
        int pk = k & 1, pp = pk ^ 1;
        float* Sk    = ws + (size_t)(2 * pk) * BN;
        float* Tk    = ws + (size_t)(2 * pk + 1) * BN;
        float* Sp    = ws + (size_t)(2 * pp) * BN;
        float* Tp    = ws + (size_t)(2 * pp + 1) * BN;
        float* RSk   = ws + (size_t)(4 + 2 * pk) * BN;
        float* RRk   = ws + (size_t)(5 + 2 * pk) * BN;
        float* RSp   = ws + (size_t)(4 + 2 * pp) * BN;
        float* RRp   = ws + (size_t)(5 + 2 * pp) * BN;
        float* curk  = ws + (size_t)(8 + pk) * BN;
        float* curp  = ws + (size_t)(8 + pp) * BN;
        float* costk = ws + (size_t)(10 + pk) * BN;
        float* costp = ws + (size_t)(10 + pp) * BN;

        // ===== phase A (R9 passA body) =====
        if (t < TILE) {                        // exactly wave 0
            int idx = base + split * TILE + t;
            const float* p = preds + (size_t)idx * 3;
            float px = p[0], py = p[1], pz = p[2];
            float pn = px * px + py * py + pz * pz;
            float cu, contrib = 0.0f;
            if (k == 0) cu = 1.0f;
            else {
                float cup = curp[idx], rs = RSp[idx], rr = RRp[idx];
                contrib = cup * rr;                       // round k-1 result term
                cu = fmaxf(cup * (1.0f - rs), 0.0f);
            }
            s_p[t]  = make_float4(px, py, pz, c1 * pn);
            s_cu[t] = cu;
            if (mc == 0) {
                curk[idx] = cu;
                RSk[idx] = 0.0f; RRk[idx] = 0.0f;         // for this round's B
            }
            if (k > 0) {
#pragma unroll
                for (int o = 32; o > 0; o >>= 1) contrib += __shfl_down(contrib, o, 64);
                if (t == 0) s_red0 = contrib;
            }
        }
        {
            int m0 = mc * CHUNK + t;
            float gx[CPT], gy[CPT], gz[CPT], am[CPT], Sa[CPT], Ta[CPT];
            float n2c1 = -2.0f * c1;
#pragma unroll
            for (int c = 0; c < CPT; c++) {
                int m = m0 + c * TPB;
                const float* l = labels + (size_t)(base + m) * 3;
                float lx = l[0], ly = l[1], lz = l[2];
                gx[c] = n2c1 * lx; gy[c] = n2c1 * ly; gz[c] = n2c1 * lz;
                am[c] = c1 * (lx * lx + ly * ly + lz * lz);
                Sa[c] = 0.0f; Ta[c] = 0.0f;
            }
            __syncthreads();
            if (k > 0 && mc == 0 && t == 0) atomicAdd(out, s_red0);

#pragma unroll 4
            for (int j = 0; j < TILE; j++) {
                float4 P = s_p[j]; float cu = s_cu[j];
#pragma unroll
                for (int c = 0; c < CPT; c++) {
                    float arg = fmaf(P.x, gx[c], fmaf(P.y, gy[c], fmaf(P.z, gz[c], P.w + am[c])));
                    float e = fast_exp2(arg);
                    Sa[c] += e;
                    Ta[c] = fmaf(e, cu, Ta[c]);
                }
            }
#pragma unroll
            for (int c = 0; c < CPT; c++) {
                int idx = base + m0 + c * TPB;
                atomicAdd(&Sk[idx], Sa[c]);
                atomicAdd(&Tk[idx], Ta[c]);
            }
        }
        gsync(grid);

        // ===== phase B (R9 passB body) =====
        if (t < TILE) {
            int idx = base + split * TILE + t;
            const float* l = labels + (size_t)idx * 3;
            float lx = l[0], ly = l[1], lz = l[2];
            float lm2 = lx * lx + ly * ly + lz * lz;
            float S = Sk[idx], T = Tk[idx];
            float cost = (k == 0) ? 1.0f : costk[idx];
            float D1 = fmaf(cost, S, EPSF);
            float S2 = cost * T / D1;
            float bw = fminf(cost / (S2 + EPSF), 1.0f);
            float cc = cost * bw / D1;
            float n2c1 = -2.0f * c1;
            s_l[t]  = make_float4(n2c1 * lx, n2c1 * ly, n2c1 * lz, c1 * lm2);
            s_cc[t] = cc;
            if (mc == 0) {
                costp[idx] = fmaxf(fmaf(-S2, bw, cost), 0.0f);
                Sp[idx] = 0.0f; Tp[idx] = 0.0f;           // for next round's A
            }
        }
        {
            int n0 = mc * CHUNK + t;
            float px[CPT], py[CPT], pz[CPT], qq[CPT], RSa[CPT], RRa[CPT];
#pragma unroll
            for (int c = 0; c < CPT; c++) {
                int n = n0 + c * TPB;
                const float* p = preds + (size_t)(base + n) * 3;
                px[c] = p[0]; py[c] = p[1]; pz[c] = p[2];
                qq[c] = c1 * (px[c] * px[c] + py[c] * py[c] + pz[c] * pz[c]);
                RSa[c] = 0.0f; RRa[c] = 0.0f;
            }
            __syncthreads();

#pragma unroll 4
            for (int j = 0; j < TILE; j++) {
                float4 L = s_l[j]; float ccj = s_cc[j];
#pragma unroll
                for (int c = 0; c < CPT; c++) {
                    float arg = fmaf(px[c], L.x, fmaf(py[c], L.y, fmaf(pz[c], L.z, qq[c] + L.w)));
                    float e = fast_exp2(arg);
                    float w = e * ccj;
                    RSa[c] += w;
                    RRa[c] = fmaf(w, arg, RRa[c]);        // sum w*arg; *1/c1 at end
                }
            }
#pragma unroll
            for (int c = 0; c < CPT; c++) {
                int idx = base + n0 + c * TPB;
                atomicAdd(&RSk[idx], RSa[c]);
                atomicAdd(&RRk[idx], RRa[c] * invc1);
            }
        }
        gsync(grid);
    }

    // ===== k9 tail (round 9, ef=0): algebraic collapse; blocks 0..15 =====
    if (blk < BB) {
        const float* cur8  = ws + (size_t)8 * BN;    // curb[0]
        const float* RS8   = ws + (size_t)4 * BN;    // RS[0]
        const float* RR8   = ws + (size_t)5 * BN;    // RR[0]
        const float* cost9 = ws + (size_t)11 * BN;   // costb[1]
        int kbase = blk * NN;

        float cu9[K9C];
        float contrib = 0.0f, csum = 0.0f;
#pragma unroll
        for (int c = 0; c < K9C; c++) {
            int idx = kbase + t + c * TPB;
            float cup = cur8[idx];
            contrib = fmaf(cup, RR8[idx], contrib);       // round-8 result term
            float cu = fmaxf(cup * (1.0f - RS8[idx]), 0.0f);
            cu9[c] = cu; csum += cu;
        }
        float contribT = block_sum(contrib, t, tmp8);
        float Cb = block_sum(csum, t, tmp8);              // T[m] == Cb for all m

        float A = 0.0f, Bs = 0.0f, Vx = 0.0f, Vy = 0.0f, Vz = 0.0f;
#pragma unroll
        for (int c = 0; c < K9C; c++) {
            int idx = kbase + t + c * TPB;
            const float* l = labels + (size_t)idx * 3;
            float lx = l[0], ly = l[1], lz = l[2];
            float cost = cost9[idx];
            float D1 = fmaf(cost, 2048.0f, EPSF);         // S == 2048 exactly
            float S2 = cost * Cb / D1;
            float bw = fminf(cost / (S2 + EPSF), 1.0f);
            float cc = cost * bw / D1;
            A += cc;
            Bs = fmaf(cc, lx * lx + ly * ly + lz * lz, Bs);
            Vx = fmaf(cc, lx, Vx); Vy = fmaf(cc, ly, Vy); Vz = fmaf(cc, lz, Vz);
        }
        float At  = block_sum(A, t, tmp8);
        float Bt  = block_sum(Bs, t, tmp8);
        float Vxt = block_sum(Vx, t, tmp8);
        float Vyt = block_sum(Vy, t, tmp8);
        float Vzt = block_sum(Vz, t, tmp8);

        float acc = 0.0f;
#pragma unroll
        for (int c = 0; c < K9C; c++) {
            int idx = kbase + t + c * TPB;
            const float* p = preds + (size_t)idx * 3;
            float x = p[0], y = p[1], z = p[2];
            float pn = x * x + y * y + z * z;
            float rr = fmaf(At, pn, Bt) - 2.0f * (x * Vxt + y * Vyt + z * Vzt);
            acc = fmaf(cu9[c], rr, acc);                  // round-9 result term
        }
        float accT = block_sum(acc, t, tmp8);
        if (t == 0) atomicAdd(out, contribT + accT);
    }
}

// ===================== fallback: R9 multi-kernel (proven PASS) ===============
__global__ __launch_bounds__(TPB, 8) void passAf(
    const float* __restrict__ preds, const float* __restrict__ labels,
    const float* __restrict__ curprev, float* __restrict__ curout,
    const float* __restrict__ RSprev, const float* __restrict__ RRprev,
    float* __restrict__ RSz, float* __restrict__ RRz,
    float* __restrict__ Sacc, float* __restrict__ Tacc,
    float* __restrict__ out, float c1, int k)
{
    __shared__ float4 s_p[TILE];
    __shared__ float  s_cu[TILE];
    __shared__ float  s_red0;
    int blk = blockIdx.x;
    int split = blk & 31, mc = (blk >> 5) & 1, b = blk >> 6;
    int t = threadIdx.x;
    int base = b * NN;

    if (t < TILE) {
        int idx = base + split * TILE + t;
        const float* p = preds + (size_t)idx * 3;
        float px = p[0], py = p[1], pz = p[2];
        float pn = px * px + py * py + pz * pz;
        float cu, contrib = 0.0f;
        if (k == 0) cu = 1.0f;
        else {
            float cup = curprev[idx], rs = RSprev[idx], rr = RRprev[idx];
            contrib = cup * rr;
            cu = fmaxf(cup * (1.0f - rs), 0.0f);
        }
        s_p[t]  = make_float4(px, py, pz, c1 * pn);
        s_cu[t] = cu;
        if (mc == 0) {
            curout[idx] = cu;
            RSz[idx] = 0.0f; RRz[idx] = 0.0f;
        }
        if (k > 0) {
#pragma unroll
            for (int o = 32; o > 0; o >>= 1) contrib += __shfl_down(contrib, o, 64);
            if (t == 0) s_red0 = contrib;
        }
    }
    int m0 = mc * CHUNK + t;
    float gx[CPT], gy[CPT], gz[CPT], am[CPT], Sa[CPT], Ta[CPT];
    float n2c1 = -2.0f * c1;
#pragma unroll
    for (int c = 0; c < CPT; c++) {
        int m = m0 + c * TPB;
        const float* l = labels + (size_t)(base + m) * 3;
        float lx = l[0], ly = l[1], lz = l[2];
        gx[c] = n2c1 * lx; gy[c] = n2c1 * ly; gz[c] = n2c1 * lz;
        am[c] = c1 * (lx * lx + ly * ly + lz * lz);
        Sa[c] = 0.0f; Ta[c] = 0.0f;
    }
    __syncthreads();
    if (k > 0 && mc == 0 && t == 0) atomicAdd(out, s_red0);

#pragma unroll 4
    for (int j = 0; j < TILE; j++) {
        float4 P = s_p[j]; float cu = s_cu[j];
#pragma unroll
        for (int c = 0; c < CPT; c++) {
            float arg = fmaf(P.x, gx[c], fmaf(P.y, gy[c], fmaf(P.z, gz[c], P.w + am[c])));
            float e = fast_exp2(arg);
            Sa[c] += e;
            Ta[c] = fmaf(e, cu, Ta[c]);
        }
    }
#pragma unroll
    for (int c = 0; c < CPT; c++) {
        int idx = base + m0 + c * TPB;
        atomicAdd(&Sacc[idx], Sa[c]);
        atomicAdd(&Tacc[idx], Ta[c]);
    }
}

__global__ __launch_bounds__(TPB, 8) void passBf(
    const float* __restrict__ preds, const float* __restrict__ labels,
    const float* __restrict__ Sread, const float* __restrict__ Tread,
    const float* __restrict__ costprev, float* __restrict__ costout,
    float* __restrict__ Sz, float* __restrict__ Tz,
    float* __restrict__ RSacc, float* __restrict__ RRacc,
    float c1, float invc1, int k)
{
    __shared__ float4 s_l[TILE];
    __shared__ float  s_cc[TILE];
    int blk = blockIdx.x;
    int split = blk & 31, nc = (blk >> 5) & 1, b = blk >> 6;
    int t = threadIdx.x;
    int base = b * NN;

    if (t < TILE) {
        int idx = base + split * TILE + t;
        const float* l = labels + (size_t)idx * 3;
        float lx = l[0], ly = l[1], lz = l[2];
        float lm2 = lx * lx + ly * ly + lz * lz;
        float S = Sread[idx], T = Tread[idx];
        float cost = (k == 0) ? 1.0f : costprev[idx];
        float D1 = fmaf(cost, S, EPSF);
        float S2 = cost * T / D1;
        float bw = fminf(cost / (S2 + EPSF), 1.0f);
        float cc = cost * bw / D1;
        float n2c1 = -2.0f * c1;
        s_l[t]  = make_float4(n2c1 * lx, n2c1 * ly, n2c1 * lz, c1 * lm2);
        s_cc[t] = cc;
        if (nc == 0) {
            costout[idx] = fmaxf(fmaf(-S2, bw, cost), 0.0f);
            Sz[idx] = 0.0f; Tz[idx] = 0.0f;
        }
    }
    int n0 = nc * CHUNK + t;
    float px[CPT], py[CPT], pz[CPT], qq[CPT], RSa[CPT], RRa[CPT];
#pragma unroll
    for (int c = 0; c < CPT; c++) {
        int n = n0 + c * TPB;
        const float* p = preds + (size_t)(base + n) * 3;
        px[c] = p[0]; py[c] = p[1]; pz[c] = p[2];
        qq[c] = c1 * (px[c] * px[c] + py[c] * py[c] + pz[c] * pz[c]);
        RSa[c] = 0.0f; RRa[c] = 0.0f;
    }
    __syncthreads();

#pragma unroll 4
    for (int j = 0; j < TILE; j++) {
        float4 L = s_l[j]; float ccj = s_cc[j];
#pragma unroll
        for (int c = 0; c < CPT; c++) {
            float arg = fmaf(px[c], L.x, fmaf(py[c], L.y, fmaf(pz[c], L.z, qq[c] + L.w)));
            float e = fast_exp2(arg);
            float w = e * ccj;
            RSa[c] += w;
            RRa[c] = fmaf(w, arg, RRa[c]);
        }
    }
#pragma unroll
    for (int c = 0; c < CPT; c++) {
        int idx = base + n0 + c * TPB;
        atomicAdd(&RSacc[idx], RSa[c]);
        atomicAdd(&RRacc[idx], RRa[c] * invc1);
    }
}

__global__ __launch_bounds__(TPB, 1) void k9f(
    const float* __restrict__ preds, const float* __restrict__ labels,
    const float* __restrict__ cur8, const float* __restrict__ RS8,
    const float* __restrict__ RR8, const float* __restrict__ cost9,
    float* __restrict__ out)
{
    __shared__ float tmp8[TPB / 64];
    int b = blockIdx.x, t = threadIdx.x;
    int base = b * NN;

    float cu9[K9C];
    float contrib = 0.0f, csum = 0.0f;
#pragma unroll
    for (int c = 0; c < K9C; c++) {
        int idx = base + t + c * TPB;
        float cup = cur8[idx];
        contrib = fmaf(cup, RR8[idx], contrib);
        float cu = fmaxf(cup * (1.0f - RS8[idx]), 0.0f);
        cu9[c] = cu; csum += cu;
    }
    float contribT = block_sum(contrib, t, tmp8);
    float Cb = block_sum(csum, t, tmp8);

    float A = 0.0f, Bs = 0.0f, Vx = 0.0f, Vy = 0.0f, Vz = 0.0f;
#pragma unroll
    for (int c = 0; c < K9C; c++) {
        int idx = base + t + c * TPB;
        const float* l = labels + (size_t)idx * 3;
        float lx = l[0], ly = l[1], lz = l[2];
        float cost = cost9[idx];
        float D1 = fmaf(cost, 2048.0f, EPSF);
        float S2 = cost * Cb / D1;
        float bw = fminf(cost / (S2 + EPSF), 1.0f);
        float cc = cost * bw / D1;
        A += cc;
        Bs = fmaf(cc, lx * lx + ly * ly + lz * lz, Bs);
        Vx = fmaf(cc, lx, Vx); Vy = fmaf(cc, ly, Vy); Vz = fmaf(cc, lz, Vz);
    }
    float At  = block_sum(A, t, tmp8);
    float Bt  = block_sum(Bs, t, tmp8);
    float Vxt = block_sum(Vx, t, tmp8);
    float Vyt = block_sum(Vy, t, tmp8);
    float Vzt = block_sum(Vz, t, tmp8);

    float acc = 0.0f;
#pragma unroll
    for (int c = 0; c < K9C; c++) {
        int idx = base + t + c * TPB;
        const float* p = preds + (size_t)idx * 3;
        float x = p[0], y = p[1], z = p[2];
        float pn = x * x + y * y + z * z;
        float rr = fmaf(At, pn, Bt) - 2.0f * (x * Vxt + y * Vyt + z * Vzt);
        acc = fmaf(cu9[c], rr, acc);
    }
    float accT = block_sum(acc, t, tmp8);
    if (t == 0) atomicAdd(out, contribT + accT);
}

extern "C" void kernel_launch(void* const* d_in, const int* in_sizes, int n_in,
                              void* d_out, int out_size, void* d_ws, size_t ws_size,
                              hipStream_t stream) {
    const float* preds  = (const float*)d_in[0];
    const float* labels = (const float*)d_in[1];
    float* out = (float*)d_out;
    float* ws  = (float*)d_ws;

    // Decide coop feasibility (deterministic per process -> same work per call).
    int nb = 0;
    hipError_t qrc = hipOccupancyMaxActiveBlocksPerMultiprocessor(
        &nb, (const void*)mega, TPB, 0);
    bool coop = (qrc == hipSuccess) && (nb * 256 >= MGRID);
    if (coop) {
        void* args[4] = {(void*)&preds, (void*)&labels, (void*)&out, (void*)&ws};
        hipError_t rc = hipLaunchCooperativeKernel((const void*)mega, dim3(MGRID),
                                                   dim3(TPB), args, 0, stream);
        if (rc != hipSuccess) coop = false;
    }
    if (!coop) {
        // R9-proven multi-kernel path
        float* S[2]     = {ws + 0 * BN, ws + 2 * BN};
        float* T[2]     = {ws + 1 * BN, ws + 3 * BN};
        float* RS[2]    = {ws + 4 * BN, ws + 6 * BN};
        float* RR[2]    = {ws + 5 * BN, ws + 7 * BN};
        float* curb[2]  = {ws + 8 * BN, ws + 9 * BN};
        float* costb[2] = {ws + 10 * BN, ws + 11 * BN};

        hipMemsetAsync(d_out, 0, sizeof(float), stream);
        hipMemsetAsync(ws, 0, (size_t)2 * BN * sizeof(float), stream);

        static const float efs[9] = {-16384.0f, -4096.0f, -1024.0f, -256.0f,
                                     -64.0f, -16.0f, -4.0f, -1.0f, -0.25f};
        const float log2e = 1.44269504088896f;
        for (int k = 0; k < 9; k++) {
            float c1 = efs[k] * log2e;
            float invc1 = 1.0f / c1;
            int pk = k & 1, pp = (k + 1) & 1;
            passAf<<<MGRID, TPB, 0, stream>>>(preds, labels,
                curb[pp], curb[pk], RS[pp], RR[pp], RS[pk], RR[pk],
                S[pk], T[pk], out, c1, k);
            passBf<<<MGRID, TPB, 0, stream>>>(preds, labels,
                S[pk], T[pk], costb[pk], costb[pp], S[pp], T[pp],
                RS[pk], RR[pk], c1, invc1, k);
        }
        k9f<<<BB, TPB, 0, stream>>>(preds, labels, curb[0], RS[0], RR[0],
                                    costb[1], out);
    }
}

// Round 13
// 308.942 us; speedup vs baseline: 1.0432x; 1.0388x over previous
//
#include <hip/hip_runtime.h>
#include <hip/hip_cooperative_groups.h>
#include <cstddef>

namespace cg = cooperative_groups;

#define BB    16
#define NN    2048
#define BN    (BB * NN)
#define EPSF  1e-9f
#define TPB   512
#define CPT   2                 // columns (rows) per thread
#define CHUNK 1024              // TPB*CPT columns per block-half
#define K9C   4                 // k9: 512 threads x 4 = 2048
// mega geometry (R2/R11-proven): 16 splits x 2 col-chunks x 16 batches = 512
#define MTILE 128
#define MGRID 512

typedef float v2f __attribute__((ext_vector_type(2)));
typedef float v4f __attribute__((ext_vector_type(4)));

// OCML native exp2 is always linkable; builtin preferred (both -> v_exp_f32).
extern "C" __device__ float __ocml_native_exp2_f32(float);
__device__ __forceinline__ float fast_exp2(float x) {
#if __has_builtin(__builtin_amdgcn_exp2f)
    return __builtin_amdgcn_exp2f(x);
#else
    return __ocml_native_exp2_f32(x);
#endif
}

// Packed fp32 (VOP3P): 2 IEEE fp32 ops per VALU issue slot. (R2-proven)
__device__ __forceinline__ v2f pk_fma(v2f a, v2f b, v2f c) {
    v2f d;
    asm("v_pk_fma_f32 %0, %1, %2, %3" : "=v"(d) : "v"(a), "v"(b), "v"(c));
    return d;
}
__device__ __forceinline__ v2f pk_add(v2f a, v2f b) {
    v2f d;
    asm("v_pk_add_f32 %0, %1, %2" : "=v"(d) : "v"(a), "v"(b));
    return d;
}
__device__ __forceinline__ v2f pk_mul(v2f a, v2f b) {
    v2f d;
    asm("v_pk_mul_f32 %0, %1, %2" : "=v"(d) : "v"(a), "v"(b));
    return d;
}

__device__ __forceinline__ float block_sum(float v, int t, float* tmp8) {
#pragma unroll
    for (int o = 32; o > 0; o >>= 1) v += __shfl_down(v, o, 64);
    __syncthreads();                       // protect tmp8 reuse across calls
    if ((t & 63) == 0) tmp8[t >> 6] = v;
    __syncthreads();
    float s = 0.0f;
#pragma unroll
    for (int w = 0; w < TPB / 64; w++) s += tmp8[w];
    return s;
}

// Release-fence, grid barrier, acquire-fence (R11/R12-proven).
__device__ __forceinline__ void gsync(cg::grid_group& g) {
    __threadfence();
    g.sync();
    __threadfence();
}

__device__ const float d_efs[9] = {-16384.0f, -4096.0f, -1024.0f, -256.0f,
                                   -64.0f, -16.0f, -4.0f, -1.0f, -0.25f};

// ======== mega: 9 rounds x {A,B} + k9 tail; pk bodies (R2) ========
__global__ __launch_bounds__(TPB, 4) void mega(
    const float* __restrict__ preds, const float* __restrict__ labels,
    float* __restrict__ out, float* __restrict__ ws)
{
    cg::grid_group grid = cg::this_grid();
    __shared__ v4f s_pa[MTILE / 2];     // A: (x0,x1,y0,y1)
    __shared__ v4f s_pb[MTILE / 2];     // A: (z0,z1,w0,w1)
    __shared__ v2f s_cu2[MTILE / 2];
    __shared__ float s_red[2];
    __shared__ v4f s_la[MTILE / 2];     // B
    __shared__ v4f s_lb[MTILE / 2];
    __shared__ v2f s_cc2[MTILE / 2];
    __shared__ float tmp8[TPB / 64];

    int blk = blockIdx.x;
    int split = blk & 15, mc = (blk >> 4) & 1, b = blk >> 5;
    int t = threadIdx.x;
    int base = b * NN;

    // init: zero S[0],T[0] (first 2*BN floats) and out (replay-correct)
    {
        int gid = blk * TPB + t;
        if (gid < 2 * BN) { ws[gid] = 0.0f; ws[gid + (MGRID * TPB < 2 * BN ? 0 : 0)] = ws[gid]; }
        // 512*512 = 262144 >= 2*BN(65536): single write covers; extra no-op above removed by compiler
        if (gid == 0) *out = 0.0f;
    }
    gsync(grid);

    const float log2e = 1.44269504088896f;
    for (int k = 0; k < 9; k++) {
        float c1 = d_efs[k] * log2e;
        float invc1 = 1.0f / c1;
        int pk = k & 1, pp = pk ^ 1;
        float* Sk    = ws + (size_t)(2 * pk) * BN;
        float* Tk    = ws + (size_t)(2 * pk + 1) * BN;
        float* Sp    = ws + (size_t)(2 * pp) * BN;
        float* Tp    = ws + (size_t)(2 * pp + 1) * BN;
        float* RSk   = ws + (size_t)(4 + 2 * pk) * BN;
        float* RRk   = ws + (size_t)(5 + 2 * pk) * BN;
        float* RSp   = ws + (size_t)(4 + 2 * pp) * BN;
        float* RRp   = ws + (size_t)(5 + 2 * pp) * BN;
        float* curk  = ws + (size_t)(8 + pk) * BN;
        float* curp  = ws + (size_t)(8 + pp) * BN;
        float* costk = ws + (size_t)(10 + pk) * BN;
        float* costp = ws + (size_t)(10 + pp) * BN;

        // ===== phase A (R2 passA body) =====
        if (t < MTILE) {
            int idx = base + split * MTILE + t;
            const float* p = preds + (size_t)idx * 3;
            float px = p[0], py = p[1], pz = p[2];
            float pn = px * px + py * py + pz * pz;
            float cu, contrib = 0.0f;
            if (k == 0) cu = 1.0f;
            else {
                float cup = curp[idx], rs = RSp[idx], rr = RRp[idx];
                contrib = cup * rr;                       // round k-1 result term
                cu = fmaxf(cup * (1.0f - rs), 0.0f);
            }
            int h = t >> 1, par = t & 1;
            float* pa = (float*)&s_pa[h];
            float* pb = (float*)&s_pb[h];
            pa[par] = px; pa[2 + par] = py;
            pb[par] = pz; pb[2 + par] = c1 * pn;
            ((float*)s_cu2)[t] = cu;
            if (mc == 0) {
                curk[idx] = cu;
                RSk[idx] = 0.0f; RRk[idx] = 0.0f;         // for this round's B
            }
            if (k > 0 && mc == 0) {                       // waves 0,1 inside t<128
#pragma unroll
                for (int o = 32; o > 0; o >>= 1) contrib += __shfl_down(contrib, o, 64);
                if ((t & 63) == 0) s_red[t >> 6] = contrib;
            }
        }
        {
            int m0 = mc * CHUNK + t;
            v2f gx2[CPT], gy2[CPT], gz2[CPT], am2[CPT], Sa2[CPT], Ta2[CPT];
            float n2c1 = -2.0f * c1;
#pragma unroll
            for (int c = 0; c < CPT; c++) {
                int m = m0 + c * TPB;
                const float* l = labels + (size_t)(base + m) * 3;
                float lx = l[0], ly = l[1], lz = l[2];
                float gx = n2c1 * lx, gy = n2c1 * ly, gz = n2c1 * lz;
                float am = c1 * (lx * lx + ly * ly + lz * lz);
                gx2[c] = (v2f){gx, gx}; gy2[c] = (v2f){gy, gy}; gz2[c] = (v2f){gz, gz};
                am2[c] = (v2f){am, am};
                Sa2[c] = (v2f){0.0f, 0.0f}; Ta2[c] = (v2f){0.0f, 0.0f};
            }
            __syncthreads();
            if (k > 0 && mc == 0 && t == 0) atomicAdd(out, s_red[0] + s_red[1]);

#pragma unroll 4
            for (int h = 0; h < MTILE / 2; h++) {
                v4f A1 = s_pa[h];
                v4f A2 = s_pb[h];
                v2f cu2 = s_cu2[h];
#pragma unroll
                for (int c = 0; c < CPT; c++) {
                    v2f seed = pk_add(A2.zw, am2[c]);
                    v2f arg = pk_fma(A1.xy, gx2[c],
                              pk_fma(A1.zw, gy2[c],
                              pk_fma(A2.xy, gz2[c], seed)));
                    v2f e2;
                    e2.x = fast_exp2(arg.x);
                    e2.y = fast_exp2(arg.y);
                    Sa2[c] = pk_add(Sa2[c], e2);
                    Ta2[c] = pk_fma(e2, cu2, Ta2[c]);
                }
            }
#pragma unroll
            for (int c = 0; c < CPT; c++) {
                int idx = base + m0 + c * TPB;
                atomicAdd(&Sk[idx], Sa2[c].x + Sa2[c].y);
                atomicAdd(&Tk[idx], Ta2[c].x + Ta2[c].y);
            }
        }
        gsync(grid);

        // ===== phase B (R2 passB body) =====
        if (t < MTILE) {
            int idx = base + split * MTILE + t;
            const float* l = labels + (size_t)idx * 3;
            float lx = l[0], ly = l[1], lz = l[2];
            float lm2 = lx * lx + ly * ly + lz * lz;
            float S = Sk[idx], T = Tk[idx];
            float cost = (k == 0) ? 1.0f : costk[idx];
            float D1 = fmaf(cost, S, EPSF);
            float S2 = cost * T / D1;
            float bw = fminf(cost / (S2 + EPSF), 1.0f);
            float cc = cost * bw / D1;
            int h = t >> 1, par = t & 1;
            float* la = (float*)&s_la[h];
            float* lb = (float*)&s_lb[h];
            float n2c1 = -2.0f * c1;
            la[par] = n2c1 * lx; la[2 + par] = n2c1 * ly;
            lb[par] = n2c1 * lz; lb[2 + par] = c1 * lm2;
            ((float*)s_cc2)[t] = cc;
            if (mc == 0) {
                costp[idx] = fmaxf(fmaf(-S2, bw, cost), 0.0f);
                Sp[idx] = 0.0f; Tp[idx] = 0.0f;           // for next round's A
            }
        }
        {
            int n0 = mc * CHUNK + t;
            v2f px2[CPT], py2[CPT], pz2[CPT], qq2[CPT], RSa2[CPT], RRa2[CPT];
#pragma unroll
            for (int c = 0; c < CPT; c++) {
                int n = n0 + c * TPB;
                const float* p = preds + (size_t)(base + n) * 3;
                float px = p[0], py = p[1], pz = p[2];
                float qq = c1 * (px * px + py * py + pz * pz);
                px2[c] = (v2f){px, px}; py2[c] = (v2f){py, py}; pz2[c] = (v2f){pz, pz};
                qq2[c] = (v2f){qq, qq};
                RSa2[c] = (v2f){0.0f, 0.0f}; RRa2[c] = (v2f){0.0f, 0.0f};
            }
            __syncthreads();

#pragma unroll 4
            for (int h = 0; h < MTILE / 2; h++) {
                v4f L1 = s_la[h];
                v4f L2 = s_lb[h];
                v2f cc2 = s_cc2[h];
#pragma unroll
                for (int c = 0; c < CPT; c++) {
                    v2f seed = pk_add(L2.zw, qq2[c]);
                    v2f arg = pk_fma(L1.xy, px2[c],
                              pk_fma(L1.zw, py2[c],
                              pk_fma(L2.xy, pz2[c], seed)));
                    v2f e2;
                    e2.x = fast_exp2(arg.x);
                    e2.y = fast_exp2(arg.y);
                    v2f w2 = pk_mul(e2, cc2);
                    RSa2[c] = pk_add(RSa2[c], w2);
                    RRa2[c] = pk_fma(w2, arg, RRa2[c]);   // sum w*arg; *1/c1 at end
                }
            }
#pragma unroll
            for (int c = 0; c < CPT; c++) {
                int idx = base + n0 + c * TPB;
                atomicAdd(&RSk[idx], RSa2[c].x + RSa2[c].y);
                atomicAdd(&RRk[idx], (RRa2[c].x + RRa2[c].y) * invc1);
            }
        }
        gsync(grid);
    }

    // ===== k9 tail (round 9, ef=0): algebraic collapse; blocks 0..15 =====
    if (blk < BB) {
        const float* cur8  = ws + (size_t)8 * BN;    // curb[0]
        const float* RS8   = ws + (size_t)4 * BN;    // RS[0]
        const float* RR8   = ws + (size_t)5 * BN;    // RR[0]
        const float* cost9 = ws + (size_t)11 * BN;   // costb[1]
        int kbase = blk * NN;

        float cu9[K9C];
        float contrib = 0.0f, csum = 0.0f;
#pragma unroll
        for (int c = 0; c < K9C; c++) {
            int idx = kbase + t + c * TPB;
            float cup = cur8[idx];
            contrib = fmaf(cup, RR8[idx], contrib);       // round-8 result term
            float cu = fmaxf(cup * (1.0f - RS8[idx]), 0.0f);
            cu9[c] = cu; csum += cu;
        }
        float contribT = block_sum(contrib, t, tmp8);
        float Cb = block_sum(csum, t, tmp8);              // T[m] == Cb for all m

        float A = 0.0f, Bs = 0.0f, Vx = 0.0f, Vy = 0.0f, Vz = 0.0f;
#pragma unroll
        for (int c = 0; c < K9C; c++) {
            int idx = kbase + t + c * TPB;
            const float* l = labels + (size_t)idx * 3;
            float lx = l[0], ly = l[1], lz = l[2];
            float cost = cost9[idx];
            float D1 = fmaf(cost, 2048.0f, EPSF);         // S == 2048 exactly
            float S2 = cost * Cb / D1;
            float bw = fminf(cost / (S2 + EPSF), 1.0f);
            float cc = cost * bw / D1;
            A += cc;
            Bs = fmaf(cc, lx * lx + ly * ly + lz * lz, Bs);
            Vx = fmaf(cc, lx, Vx); Vy = fmaf(cc, ly, Vy); Vz = fmaf(cc, lz, Vz);
        }
        float At  = block_sum(A, t, tmp8);
        float Bt  = block_sum(Bs, t, tmp8);
        float Vxt = block_sum(Vx, t, tmp8);
        float Vyt = block_sum(Vy, t, tmp8);
        float Vzt = block_sum(Vz, t, tmp8);

        float acc = 0.0f;
#pragma unroll
        for (int c = 0; c < K9C; c++) {
            int idx = kbase + t + c * TPB;
            const float* p = preds + (size_t)idx * 3;
            float x = p[0], y = p[1], z = p[2];
            float pn = x * x + y * y + z * z;
            float rr = fmaf(At, pn, Bt) - 2.0f * (x * Vxt + y * Vyt + z * Vzt);
            acc = fmaf(cu9[c], rr, acc);                  // round-9 result term
        }
        float accT = block_sum(acc, t, tmp8);
        if (t == 0) atomicAdd(out, contribT + accT);
    }
}

// ============== fallback: R2 multi-kernel pk path (proven 308) ==============
__global__ __launch_bounds__(TPB, 4) void passAf(
    const float* __restrict__ preds, const float* __restrict__ labels,
    const float* __restrict__ curprev, float* __restrict__ curout,
    const float* __restrict__ RSprev, const float* __restrict__ RRprev,
    float* __restrict__ RSz, float* __restrict__ RRz,
    float* __restrict__ Sacc, float* __restrict__ Tacc,
    float* __restrict__ out, float c1, int k)
{
    __shared__ v4f s_pa[MTILE / 2];
    __shared__ v4f s_pb[MTILE / 2];
    __shared__ v2f s_cu2[MTILE / 2];
    __shared__ float s_red[2];
    int blk = blockIdx.x;
    int split = blk & 15, mc = (blk >> 4) & 1, b = blk >> 5;
    int t = threadIdx.x;
    int base = b * NN;

    if (t < MTILE) {
        int idx = base + split * MTILE + t;
        const float* p = preds + (size_t)idx * 3;
        float px = p[0], py = p[1], pz = p[2];
        float pn = px * px + py * py + pz * pz;
        float cu, contrib = 0.0f;
        if (k == 0) cu = 1.0f;
        else {
            float cup = curprev[idx], rs = RSprev[idx], rr = RRprev[idx];
            contrib = cup * rr;
            cu = fmaxf(cup * (1.0f - rs), 0.0f);
        }
        int h = t >> 1, par = t & 1;
        float* pa = (float*)&s_pa[h];
        float* pb = (float*)&s_pb[h];
        pa[par] = px; pa[2 + par] = py;
        pb[par] = pz; pb[2 + par] = c1 * pn;
        ((float*)s_cu2)[t] = cu;
        if (mc == 0) {
            curout[idx] = cu;
            RSz[idx] = 0.0f; RRz[idx] = 0.0f;
        }
        if (k > 0 && mc == 0) {
#pragma unroll
            for (int o = 32; o > 0; o >>= 1) contrib += __shfl_down(contrib, o, 64);
            if ((t & 63) == 0) s_red[t >> 6] = contrib;
        }
    }

    int m0 = mc * CHUNK + t;
    v2f gx2[CPT], gy2[CPT], gz2[CPT], am2[CPT], Sa2[CPT], Ta2[CPT];
    float n2c1 = -2.0f * c1;
#pragma unroll
    for (int c = 0; c < CPT; c++) {
        int m = m0 + c * TPB;
        const float* l = labels + (size_t)(base + m) * 3;
        float lx = l[0], ly = l[1], lz = l[2];
        float gx = n2c1 * lx, gy = n2c1 * ly, gz = n2c1 * lz;
        float am = c1 * (lx * lx + ly * ly + lz * lz);
        gx2[c] = (v2f){gx, gx}; gy2[c] = (v2f){gy, gy}; gz2[c] = (v2f){gz, gz};
        am2[c] = (v2f){am, am};
        Sa2[c] = (v2f){0.0f, 0.0f}; Ta2[c] = (v2f){0.0f, 0.0f};
    }
    __syncthreads();
    if (k > 0 && mc == 0 && t == 0) atomicAdd(out, s_red[0] + s_red[1]);

#pragma unroll 4
    for (int h = 0; h < MTILE / 2; h++) {
        v4f A1 = s_pa[h];
        v4f A2 = s_pb[h];
        v2f cu2 = s_cu2[h];
#pragma unroll
        for (int c = 0; c < CPT; c++) {
            v2f seed = pk_add(A2.zw, am2[c]);
            v2f arg = pk_fma(A1.xy, gx2[c],
                      pk_fma(A1.zw, gy2[c],
                      pk_fma(A2.xy, gz2[c], seed)));
            v2f e2;
            e2.x = fast_exp2(arg.x);
            e2.y = fast_exp2(arg.y);
            Sa2[c] = pk_add(Sa2[c], e2);
            Ta2[c] = pk_fma(e2, cu2, Ta2[c]);
        }
    }
#pragma unroll
    for (int c = 0; c < CPT; c++) {
        int idx = base + m0 + c * TPB;
        atomicAdd(&Sacc[idx], Sa2[c].x + Sa2[c].y);
        atomicAdd(&Tacc[idx], Ta2[c].x + Ta2[c].y);
    }
}

__global__ __launch_bounds__(TPB, 4) void passBf(
    const float* __restrict__ preds, const float* __restrict__ labels,
    const float* __restrict__ Sread, const float* __restrict__ Tread,
    const float* __restrict__ costprev, float* __restrict__ costout,
    float* __restrict__ Sz, float* __restrict__ Tz,
    float* __restrict__ RSacc, float* __restrict__ RRacc,
    float c1, float invc1, int k)
{
    __shared__ v4f s_la[MTILE / 2];
    __shared__ v4f s_lb[MTILE / 2];
    __shared__ v2f s_cc2[MTILE / 2];
    int blk = blockIdx.x;
    int split = blk & 15, nc = (blk >> 4) & 1, b = blk >> 5;
    int t = threadIdx.x;
    int base = b * NN;

    if (t < MTILE) {
        int idx = base + split * MTILE + t;
        const float* l = labels + (size_t)idx * 3;
        float lx = l[0], ly = l[1], lz = l[2];
        float lm2 = lx * lx + ly * ly + lz * lz;
        float S = Sread[idx], T = Tread[idx];
        float cost = (k == 0) ? 1.0f : costprev[idx];
        float D1 = fmaf(cost, S, EPSF);
        float S2 = cost * T / D1;
        float bw = fminf(cost / (S2 + EPSF), 1.0f);
        float cc = cost * bw / D1;
        int h = t >> 1, par = t & 1;
        float* la = (float*)&s_la[h];
        float* lb = (float*)&s_lb[h];
        float n2c1 = -2.0f * c1;
        la[par] = n2c1 * lx; la[2 + par] = n2c1 * ly;
        lb[par] = n2c1 * lz; lb[2 + par] = c1 * lm2;
        ((float*)s_cc2)[t] = cc;
        if (nc == 0) {
            costout[idx] = fmaxf(fmaf(-S2, bw, cost), 0.0f);
            Sz[idx] = 0.0f; Tz[idx] = 0.0f;
        }
    }

    int n0 = nc * CHUNK + t;
    v2f px2[CPT], py2[CPT], pz2[CPT], qq2[CPT], RSa2[CPT], RRa2[CPT];
#pragma unroll
    for (int c = 0; c < CPT; c++) {
        int n = n0 + c * TPB;
        const float* p = preds + (size_t)(base + n) * 3;
        float px = p[0], py = p[1], pz = p[2];
        float qq = c1 * (px * px + py * py + pz * pz);
        px2[c] = (v2f){px, px}; py2[c] = (v2f){py, py}; pz2[c] = (v2f){pz, pz};
        qq2[c] = (v2f){qq, qq};
        RSa2[c] = (v2f){0.0f, 0.0f}; RRa2[c] = (v2f){0.0f, 0.0f};
    }
    __syncthreads();

#pragma unroll 4
    for (int h = 0; h < MTILE / 2; h++) {
        v4f L1 = s_la[h];
        v4f L2 = s_lb[h];
        v2f cc2 = s_cc2[h];
#pragma unroll
        for (int c = 0; c < CPT; c++) {
            v2f seed = pk_add(L2.zw, qq2[c]);
            v2f arg = pk_fma(L1.xy, px2[c],
                      pk_fma(L1.zw, py2[c],
                      pk_fma(L2.xy, pz2[c], seed)));
            v2f e2;
            e2.x = fast_exp2(arg.x);
            e2.y = fast_exp2(arg.y);
            v2f w2 = pk_mul(e2, cc2);
            RSa2[c] = pk_add(RSa2[c], w2);
            RRa2[c] = pk_fma(w2, arg, RRa2[c]);
        }
    }
#pragma unroll
    for (int c = 0; c < CPT; c++) {
        int idx = base + n0 + c * TPB;
        atomicAdd(&RSacc[idx], RSa2[c].x + RSa2[c].y);
        atomicAdd(&RRacc[idx], (RRa2[c].x + RRa2[c].y) * invc1);
    }
}

__global__ __launch_bounds__(TPB, 1) void k9f(
    const float* __restrict__ preds, const float* __restrict__ labels,
    const float* __restrict__ cur8, const float* __restrict__ RS8,
    const float* __restrict__ RR8, const float* __restrict__ cost9,
    float* __restrict__ out)
{
    __shared__ float tmp8[TPB / 64];
    int b = blockIdx.x, t = threadIdx.x;
    int base = b * NN;

    float cu9[K9C];
    float contrib = 0.0f, csum = 0.0f;
#pragma unroll
    for (int c = 0; c < K9C; c++) {
        int idx = base + t + c * TPB;
        float cup = cur8[idx];
        contrib = fmaf(cup, RR8[idx], contrib);
        float cu = fmaxf(cup * (1.0f - RS8[idx]), 0.0f);
        cu9[c] = cu; csum += cu;
    }
    float contribT = block_sum(contrib, t, tmp8);
    float Cb = block_sum(csum, t, tmp8);

    float A = 0.0f, Bs = 0.0f, Vx = 0.0f, Vy = 0.0f, Vz = 0.0f;
#pragma unroll
    for (int c = 0; c < K9C; c++) {
        int idx = base + t + c * TPB;
        const float* l = labels + (size_t)idx * 3;
        float lx = l[0], ly = l[1], lz = l[2];
        float cost = cost9[idx];
        float D1 = fmaf(cost, 2048.0f, EPSF);
        float S2 = cost * Cb / D1;
        float bw = fminf(cost / (S2 + EPSF), 1.0f);
        float cc = cost * bw / D1;
        A += cc;
        Bs = fmaf(cc, lx * lx + ly * ly + lz * lz, Bs);
        Vx = fmaf(cc, lx, Vx); Vy = fmaf(cc, ly, Vy); Vz = fmaf(cc, lz, Vz);
    }
    float At  = block_sum(A, t, tmp8);
    float Bt  = block_sum(Bs, t, tmp8);
    float Vxt = block_sum(Vx, t, tmp8);
    float Vyt = block_sum(Vy, t, tmp8);
    float Vzt = block_sum(Vz, t, tmp8);

    float acc = 0.0f;
#pragma unroll
    for (int c = 0; c < K9C; c++) {
        int idx = base + t + c * TPB;
        const float* p = preds + (size_t)idx * 3;
        float x = p[0], y = p[1], z = p[2];
        float pn = x * x + y * y + z * z;
        float rr = fmaf(At, pn, Bt) - 2.0f * (x * Vxt + y * Vyt + z * Vzt);
        acc = fmaf(cu9[c], rr, acc);
    }
    float accT = block_sum(acc, t, tmp8);
    if (t == 0) atomicAdd(out, contribT + accT);
}

extern "C" void kernel_launch(void* const* d_in, const int* in_sizes, int n_in,
                              void* d_out, int out_size, void* d_ws, size_t ws_size,
                              hipStream_t stream) {
    const float* preds  = (const float*)d_in[0];
    const float* labels = (const float*)d_in[1];
    float* out = (float*)d_out;
    float* ws  = (float*)d_ws;

    // Coop feasibility (deterministic per process -> same work every call).
    int nb = 0;
    hipError_t qrc = hipOccupancyMaxActiveBlocksPerMultiprocessor(
        &nb, (const void*)mega, TPB, 0);
    bool coop = (qrc == hipSuccess) && (nb * 256 >= MGRID);
    if (coop) {
        void* args[4] = {(void*)&preds, (void*)&labels, (void*)&out, (void*)&ws};
        hipError_t rc = hipLaunchCooperativeKernel((const void*)mega, dim3(MGRID),
                                                   dim3(TPB), args, 0, stream);
        if (rc != hipSuccess) coop = false;
    }
    if (!coop) {
        // R2-proven multi-kernel pk path
        float* S[2]     = {ws + 0 * BN, ws + 2 * BN};
        float* T[2]     = {ws + 1 * BN, ws + 3 * BN};
        float* RS[2]    = {ws + 4 * BN, ws + 6 * BN};
        float* RR[2]    = {ws + 5 * BN, ws + 7 * BN};
        float* curb[2]  = {ws + 8 * BN, ws + 9 * BN};
        float* costb[2] = {ws + 10 * BN, ws + 11 * BN};

        hipMemsetAsync(d_out, 0, sizeof(float), stream);
        hipMemsetAsync(ws, 0, (size_t)2 * BN * sizeof(float), stream);

        static const float efs[9] = {-16384.0f, -4096.0f, -1024.0f, -256.0f,
                                     -64.0f, -16.0f, -4.0f, -1.0f, -0.25f};
        const float log2e = 1.44269504088896f;
        for (int k = 0; k < 9; k++) {
            float c1 = efs[k] * log2e;
            float invc1 = 1.0f / c1;
            int pk = k & 1, pp = (k + 1) & 1;
            passAf<<<MGRID, TPB, 0, stream>>>(preds, labels,
                curb[pp], curb[pk], RS[pp], RR[pp], RS[pk], RR[pk],
                S[pk], T[pk], out, c1, k);
            passBf<<<MGRID, TPB, 0, stream>>>(preds, labels,
                S[pk], T[pk], costb[pk], costb[pp], S[pp], T[pp],
                RS[pk], RR[pk], c1, invc1, k);
        }
        k9f<<<BB, TPB, 0, stream>>>(preds, labels, curb[0], RS[0], RR[0],
                                    costb[1], out);
    }
}

// Round 15
// 308.181 us; speedup vs baseline: 1.0458x; 1.0025x over previous
//
#include <hip/hip_runtime.h>
#include <hip/hip_cooperative_groups.h>
#include <cstddef>

namespace cg = cooperative_groups;

#define BB    16
#define NN    2048
#define BN    (BB * NN)
#define EPSF  1e-9f
#define TPB   512
#define CPT   2                 // columns (rows) per thread
#define CHUNK 1024              // TPB*CPT columns per block-half
#define K9C   4                 // k9: 512 threads x 4 = 2048
// mega geometry (R2/R11-proven): 16 splits x 2 col-chunks x 16 batches = 512
#define MTILE 128
#define MGRID 512

typedef float v2f __attribute__((ext_vector_type(2)));
typedef float v4f __attribute__((ext_vector_type(4)));

// OCML native exp2 is always linkable; builtin preferred (both -> v_exp_f32).
extern "C" __device__ float __ocml_native_exp2_f32(float);
__device__ __forceinline__ float fast_exp2(float x) {
#if __has_builtin(__builtin_amdgcn_exp2f)
    return __builtin_amdgcn_exp2f(x);
#else
    return __ocml_native_exp2_f32(x);
#endif
}

// Packed fp32 (VOP3P): 2 IEEE fp32 ops per VALU issue slot. (R2-proven)
__device__ __forceinline__ v2f pk_fma(v2f a, v2f b, v2f c) {
    v2f d;
    asm("v_pk_fma_f32 %0, %1, %2, %3" : "=v"(d) : "v"(a), "v"(b), "v"(c));
    return d;
}
__device__ __forceinline__ v2f pk_add(v2f a, v2f b) {
    v2f d;
    asm("v_pk_add_f32 %0, %1, %2" : "=v"(d) : "v"(a), "v"(b));
    return d;
}
__device__ __forceinline__ v2f pk_mul(v2f a, v2f b) {
    v2f d;
    asm("v_pk_mul_f32 %0, %1, %2" : "=v"(d) : "v"(a), "v"(b));
    return d;
}

__device__ __forceinline__ float block_sum(float v, int t, float* tmp8) {
#pragma unroll
    for (int o = 32; o > 0; o >>= 1) v += __shfl_down(v, o, 64);
    __syncthreads();                       // protect tmp8 reuse across calls
    if ((t & 63) == 0) tmp8[t >> 6] = v;
    __syncthreads();
    float s = 0.0f;
#pragma unroll
    for (int w = 0; w < TPB / 64; w++) s += tmp8[w];
    return s;
}

// Release-fence, grid barrier, acquire-fence (R11/R12/R13-proven; profiling-safe
// unlike raw spin barriers, which hung the GPU under rocprof replay in R14).
__device__ __forceinline__ void gsync(cg::grid_group& g) {
    __threadfence();
    g.sync();
    __threadfence();
}

__device__ const float d_efs[9] = {-16384.0f, -4096.0f, -1024.0f, -256.0f,
                                   -64.0f, -16.0f, -4.0f, -1.0f, -0.25f};

// ======== mega: 9 rounds x {A,B} + k9 tail; pk bodies (R2) ========
__global__ __launch_bounds__(TPB, 4) void mega(
    const float* __restrict__ preds, const float* __restrict__ labels,
    float* __restrict__ out, float* __restrict__ ws)
{
    cg::grid_group grid = cg::this_grid();
    __shared__ v4f s_pa[MTILE / 2];     // A: (x0,x1,y0,y1)
    __shared__ v4f s_pb[MTILE / 2];     // A: (z0,z1,w0,w1)
    __shared__ v2f s_cu2[MTILE / 2];
    __shared__ float s_red[2];
    __shared__ v4f s_la[MTILE / 2];     // B
    __shared__ v4f s_lb[MTILE / 2];
    __shared__ v2f s_cc2[MTILE / 2];
    __shared__ float tmp8[TPB / 64];

    int blk = blockIdx.x;
    int split = blk & 15, mc = (blk >> 4) & 1, b = blk >> 5;
    int t = threadIdx.x;
    int base = b * NN;

    // init: zero S[0],T[0] (first 2*BN floats) and out (replay-correct)
    {
        int gid = blk * TPB + t;
        if (gid < 2 * BN) ws[gid] = 0.0f;
        if (gid == 0) *out = 0.0f;
    }
    gsync(grid);

    const float log2e = 1.44269504088896f;
    for (int k = 0; k < 9; k++) {
        float c1 = d_efs[k] * log2e;
        float invc1 = 1.0f / c1;
        int pk = k & 1, pp = pk ^ 1;
        float* Sk    = ws + (size_t)(2 * pk) * BN;
        float* Tk    = ws + (size_t)(2 * pk + 1) * BN;
        float* Sp    = ws + (size_t)(2 * pp) * BN;
        float* Tp    = ws + (size_t)(2 * pp + 1) * BN;
        float* RSk   = ws + (size_t)(4 + 2 * pk) * BN;
        float* RRk   = ws + (size_t)(5 + 2 * pk) * BN;
        float* RSp   = ws + (size_t)(4 + 2 * pp) * BN;
        float* RRp   = ws + (size_t)(5 + 2 * pp) * BN;
        float* curk  = ws + (size_t)(8 + pk) * BN;
        float* curp  = ws + (size_t)(8 + pp) * BN;
        float* costk = ws + (size_t)(10 + pk) * BN;
        float* costp = ws + (size_t)(10 + pp) * BN;

        // ===== phase A (R2 passA body) =====
        if (t < MTILE) {
            int idx = base + split * MTILE + t;
            const float* p = preds + (size_t)idx * 3;
            float px = p[0], py = p[1], pz = p[2];
            float pn = px * px + py * py + pz * pz;
            float cu, contrib = 0.0f;
            if (k == 0) cu = 1.0f;
            else {
                float cup = curp[idx], rs = RSp[idx], rr = RRp[idx];
                contrib = cup * rr;                       // round k-1 result term
                cu = fmaxf(cup * (1.0f - rs), 0.0f);
            }
            int h = t >> 1, par = t & 1;
            float* pa = (float*)&s_pa[h];
            float* pb = (float*)&s_pb[h];
            pa[par] = px; pa[2 + par] = py;
            pb[par] = pz; pb[2 + par] = c1 * pn;
            ((float*)s_cu2)[t] = cu;
            if (mc == 0) {
                curk[idx] = cu;
                RSk[idx] = 0.0f; RRk[idx] = 0.0f;         // for this round's B
            }
            if (k > 0 && mc == 0) {                       // waves 0,1 inside t<128
#pragma unroll
                for (int o = 32; o > 0; o >>= 1) contrib += __shfl_down(contrib, o, 64);
                if ((t & 63) == 0) s_red[t >> 6] = contrib;
            }
        }
        {
            int m0 = mc * CHUNK + t;
            v2f gx2[CPT], gy2[CPT], gz2[CPT], am2[CPT], Sa2[CPT], Ta2[CPT];
            float n2c1 = -2.0f * c1;
#pragma unroll
            for (int c = 0; c < CPT; c++) {
                int m = m0 + c * TPB;
                const float* l = labels + (size_t)(base + m) * 3;
                float lx = l[0], ly = l[1], lz = l[2];
                float gx = n2c1 * lx, gy = n2c1 * ly, gz = n2c1 * lz;
                float am = c1 * (lx * lx + ly * ly + lz * lz);
                gx2[c] = (v2f){gx, gx}; gy2[c] = (v2f){gy, gy}; gz2[c] = (v2f){gz, gz};
                am2[c] = (v2f){am, am};
                Sa2[c] = (v2f){0.0f, 0.0f}; Ta2[c] = (v2f){0.0f, 0.0f};
            }
            __syncthreads();
            if (k > 0 && mc == 0 && t == 0) atomicAdd(out, s_red[0] + s_red[1]);

#pragma unroll 4
            for (int h = 0; h < MTILE / 2; h++) {
                v4f A1 = s_pa[h];
                v4f A2 = s_pb[h];
                v2f cu2 = s_cu2[h];
#pragma unroll
                for (int c = 0; c < CPT; c++) {
                    v2f seed = pk_add(A2.zw, am2[c]);
                    v2f arg = pk_fma(A1.xy, gx2[c],
                              pk_fma(A1.zw, gy2[c],
                              pk_fma(A2.xy, gz2[c], seed)));
                    v2f e2;
                    e2.x = fast_exp2(arg.x);
                    e2.y = fast_exp2(arg.y);
                    Sa2[c] = pk_add(Sa2[c], e2);
                    Ta2[c] = pk_fma(e2, cu2, Ta2[c]);
                }
            }
#pragma unroll
            for (int c = 0; c < CPT; c++) {
                int idx = base + m0 + c * TPB;
                atomicAdd(&Sk[idx], Sa2[c].x + Sa2[c].y);
                atomicAdd(&Tk[idx], Ta2[c].x + Ta2[c].y);
            }
        }
        gsync(grid);

        // ===== phase B (R2 passB body) =====
        if (t < MTILE) {
            int idx = base + split * MTILE + t;
            const float* l = labels + (size_t)idx * 3;
            float lx = l[0], ly = l[1], lz = l[2];
            float lm2 = lx * lx + ly * ly + lz * lz;
            float S = Sk[idx], T = Tk[idx];
            float cost = (k == 0) ? 1.0f : costk[idx];
            float D1 = fmaf(cost, S, EPSF);
            float S2 = cost * T / D1;
            float bw = fminf(cost / (S2 + EPSF), 1.0f);
            float cc = cost * bw / D1;
            int h = t >> 1, par = t & 1;
            float* la = (float*)&s_la[h];
            float* lb = (float*)&s_lb[h];
            float n2c1 = -2.0f * c1;
            la[par] = n2c1 * lx; la[2 + par] = n2c1 * ly;
            lb[par] = n2c1 * lz; lb[2 + par] = c1 * lm2;
            ((float*)s_cc2)[t] = cc;
            if (mc == 0) {
                costp[idx] = fmaxf(fmaf(-S2, bw, cost), 0.0f);
                Sp[idx] = 0.0f; Tp[idx] = 0.0f;           // for next round's A
            }
        }
        {
            int n0 = mc * CHUNK + t;
            v2f px2[CPT], py2[CPT], pz2[CPT], qq2[CPT], RSa2[CPT], RRa2[CPT];
#pragma unroll
            for (int c = 0; c < CPT; c++) {
                int n = n0 + c * TPB;
                const float* p = preds + (size_t)(base + n) * 3;
                float px = p[0], py = p[1], pz = p[2];
                float qq = c1 * (px * px + py * py + pz * pz);
                px2[c] = (v2f){px, px}; py2[c] = (v2f){py, py}; pz2[c] = (v2f){pz, pz};
                qq2[c] = (v2f){qq, qq};
                RSa2[c] = (v2f){0.0f, 0.0f}; RRa2[c] = (v2f){0.0f, 0.0f};
            }
            __syncthreads();

#pragma unroll 4
            for (int h = 0; h < MTILE / 2; h++) {
                v4f L1 = s_la[h];
                v4f L2 = s_lb[h];
                v2f cc2 = s_cc2[h];
#pragma unroll
                for (int c = 0; c < CPT; c++) {
                    v2f seed = pk_add(L2.zw, qq2[c]);
                    v2f arg = pk_fma(L1.xy, px2[c],
                              pk_fma(L1.zw, py2[c],
                              pk_fma(L2.xy, pz2[c], seed)));
                    v2f e2;
                    e2.x = fast_exp2(arg.x);
                    e2.y = fast_exp2(arg.y);
                    v2f w2 = pk_mul(e2, cc2);
                    RSa2[c] = pk_add(RSa2[c], w2);
                    RRa2[c] = pk_fma(w2, arg, RRa2[c]);   // sum w*arg; *1/c1 at end
                }
            }
#pragma unroll
            for (int c = 0; c < CPT; c++) {
                int idx = base + n0 + c * TPB;
                atomicAdd(&RSk[idx], RSa2[c].x + RSa2[c].y);
                atomicAdd(&RRk[idx], (RRa2[c].x + RRa2[c].y) * invc1);
            }
        }
        gsync(grid);
    }

    // ===== k9 tail (round 9, ef=0): algebraic collapse; blocks 0..15 =====
    if (blk < BB) {
        const float* cur8  = ws + (size_t)8 * BN;    // curb[0]
        const float* RS8   = ws + (size_t)4 * BN;    // RS[0]
        const float* RR8   = ws + (size_t)5 * BN;    // RR[0]
        const float* cost9 = ws + (size_t)11 * BN;   // costb[1]
        int kbase = blk * NN;

        float cu9[K9C];
        float contrib = 0.0f, csum = 0.0f;
#pragma unroll
        for (int c = 0; c < K9C; c++) {
            int idx = kbase + t + c * TPB;
            float cup = cur8[idx];
            contrib = fmaf(cup, RR8[idx], contrib);       // round-8 result term
            float cu = fmaxf(cup * (1.0f - RS8[idx]), 0.0f);
            cu9[c] = cu; csum += cu;
        }
        float contribT = block_sum(contrib, t, tmp8);
        float Cb = block_sum(csum, t, tmp8);              // T[m] == Cb for all m

        float A = 0.0f, Bs = 0.0f, Vx = 0.0f, Vy = 0.0f, Vz = 0.0f;
#pragma unroll
        for (int c = 0; c < K9C; c++) {
            int idx = kbase + t + c * TPB;
            const float* l = labels + (size_t)idx * 3;
            float lx = l[0], ly = l[1], lz = l[2];
            float cost = cost9[idx];
            float D1 = fmaf(cost, 2048.0f, EPSF);         // S == 2048 exactly
            float S2 = cost * Cb / D1;
            float bw = fminf(cost / (S2 + EPSF), 1.0f);
            float cc = cost * bw / D1;
            A += cc;
            Bs = fmaf(cc, lx * lx + ly * ly + lz * lz, Bs);
            Vx = fmaf(cc, lx, Vx); Vy = fmaf(cc, ly, Vy); Vz = fmaf(cc, lz, Vz);
        }
        float At  = block_sum(A, t, tmp8);
        float Bt  = block_sum(Bs, t, tmp8);
        float Vxt = block_sum(Vx, t, tmp8);
        float Vyt = block_sum(Vy, t, tmp8);
        float Vzt = block_sum(Vz, t, tmp8);

        float acc = 0.0f;
#pragma unroll
        for (int c = 0; c < K9C; c++) {
            int idx = kbase + t + c * TPB;
            const float* p = preds + (size_t)idx * 3;
            float x = p[0], y = p[1], z = p[2];
            float pn = x * x + y * y + z * z;
            float rr = fmaf(At, pn, Bt) - 2.0f * (x * Vxt + y * Vyt + z * Vzt);
            acc = fmaf(cu9[c], rr, acc);                  // round-9 result term
        }
        float accT = block_sum(acc, t, tmp8);
        if (t == 0) atomicAdd(out, contribT + accT);
    }
}

// ============== fallback: R2 multi-kernel pk path (proven 308) ==============
__global__ __launch_bounds__(TPB, 4) void passAf(
    const float* __restrict__ preds, const float* __restrict__ labels,
    const float* __restrict__ curprev, float* __restrict__ curout,
    const float* __restrict__ RSprev, const float* __restrict__ RRprev,
    float* __restrict__ RSz, float* __restrict__ RRz,
    float* __restrict__ Sacc, float* __restrict__ Tacc,
    float* __restrict__ out, float c1, int k)
{
    __shared__ v4f s_pa[MTILE / 2];
    __shared__ v4f s_pb[MTILE / 2];
    __shared__ v2f s_cu2[MTILE / 2];
    __shared__ float s_red[2];
    int blk = blockIdx.x;
    int split = blk & 15, mc = (blk >> 4) & 1, b = blk >> 5;
    int t = threadIdx.x;
    int base = b * NN;

    if (t < MTILE) {
        int idx = base + split * MTILE + t;
        const float* p = preds + (size_t)idx * 3;
        float px = p[0], py = p[1], pz = p[2];
        float pn = px * px + py * py + pz * pz;
        float cu, contrib = 0.0f;
        if (k == 0) cu = 1.0f;
        else {
            float cup = curprev[idx], rs = RSprev[idx], rr = RRprev[idx];
            contrib = cup * rr;
            cu = fmaxf(cup * (1.0f - rs), 0.0f);
        }
        int h = t >> 1, par = t & 1;
        float* pa = (float*)&s_pa[h];
        float* pb = (float*)&s_pb[h];
        pa[par] = px; pa[2 + par] = py;
        pb[par] = pz; pb[2 + par] = c1 * pn;
        ((float*)s_cu2)[t] = cu;
        if (mc == 0) {
            curout[idx] = cu;
            RSz[idx] = 0.0f; RRz[idx] = 0.0f;
        }
        if (k > 0 && mc == 0) {
#pragma unroll
            for (int o = 32; o > 0; o >>= 1) contrib += __shfl_down(contrib, o, 64);
            if ((t & 63) == 0) s_red[t >> 6] = contrib;
        }
    }

    int m0 = mc * CHUNK + t;
    v2f gx2[CPT], gy2[CPT], gz2[CPT], am2[CPT], Sa2[CPT], Ta2[CPT];
    float n2c1 = -2.0f * c1;
#pragma unroll
    for (int c = 0; c < CPT; c++) {
        int m = m0 + c * TPB;
        const float* l = labels + (size_t)(base + m) * 3;
        float lx = l[0], ly = l[1], lz = l[2];
        float gx = n2c1 * lx, gy = n2c1 * ly, gz = n2c1 * lz;
        float am = c1 * (lx * lx + ly * ly + lz * lz);
        gx2[c] = (v2f){gx, gx}; gy2[c] = (v2f){gy, gy}; gz2[c] = (v2f){gz, gz};
        am2[c] = (v2f){am, am};
        Sa2[c] = (v2f){0.0f, 0.0f}; Ta2[c] = (v2f){0.0f, 0.0f};
    }
    __syncthreads();
    if (k > 0 && mc == 0 && t == 0) atomicAdd(out, s_red[0] + s_red[1]);

#pragma unroll 4
    for (int h = 0; h < MTILE / 2; h++) {
        v4f A1 = s_pa[h];
        v4f A2 = s_pb[h];
        v2f cu2 = s_cu2[h];
#pragma unroll
        for (int c = 0; c < CPT; c++) {
            v2f seed = pk_add(A2.zw, am2[c]);
            v2f arg = pk_fma(A1.xy, gx2[c],
                      pk_fma(A1.zw, gy2[c],
                      pk_fma(A2.xy, gz2[c], seed)));
            v2f e2;
            e2.x = fast_exp2(arg.x);
            e2.y = fast_exp2(arg.y);
            Sa2[c] = pk_add(Sa2[c], e2);
            Ta2[c] = pk_fma(e2, cu2, Ta2[c]);
        }
    }
#pragma unroll
    for (int c = 0; c < CPT; c++) {
        int idx = base + m0 + c * TPB;
        atomicAdd(&Sacc[idx], Sa2[c].x + Sa2[c].y);
        atomicAdd(&Tacc[idx], Ta2[c].x + Ta2[c].y);
    }
}

__global__ __launch_bounds__(TPB, 4) void passBf(
    const float* __restrict__ preds, const float* __restrict__ labels,
    const float* __restrict__ Sread, const float* __restrict__ Tread,
    const float* __restrict__ costprev, float* __restrict__ costout,
    float* __restrict__ Sz, float* __restrict__ Tz,
    float* __restrict__ RSacc, float* __restrict__ RRacc,
    float c1, float invc1, int k)
{
    __shared__ v4f s_la[MTILE / 2];
    __shared__ v4f s_lb[MTILE / 2];
    __shared__ v2f s_cc2[MTILE / 2];
    int blk = blockIdx.x;
    int split = blk & 15, nc = (blk >> 4) & 1, b = blk >> 5;
    int t = threadIdx.x;
    int base = b * NN;

    if (t < MTILE) {
        int idx = base + split * MTILE + t;
        const float* l = labels + (size_t)idx * 3;
        float lx = l[0], ly = l[1], lz = l[2];
        float lm2 = lx * lx + ly * ly + lz * lz;
        float S = Sread[idx], T = Tread[idx];
        float cost = (k == 0) ? 1.0f : costprev[idx];
        float D1 = fmaf(cost, S, EPSF);
        float S2 = cost * T / D1;
        float bw = fminf(cost / (S2 + EPSF), 1.0f);
        float cc = cost * bw / D1;
        int h = t >> 1, par = t & 1;
        float* la = (float*)&s_la[h];
        float* lb = (float*)&s_lb[h];
        float n2c1 = -2.0f * c1;
        la[par] = n2c1 * lx; la[2 + par] = n2c1 * ly;
        lb[par] = n2c1 * lz; lb[2 + par] = c1 * lm2;
        ((float*)s_cc2)[t] = cc;
        if (nc == 0) {
            costout[idx] = fmaxf(fmaf(-S2, bw, cost), 0.0f);
            Sz[idx] = 0.0f; Tz[idx] = 0.0f;
        }
    }

    int n0 = nc * CHUNK + t;
    v2f px2[CPT], py2[CPT], pz2[CPT], qq2[CPT], RSa2[CPT], RRa2[CPT];
#pragma unroll
    for (int c = 0; c < CPT; c++) {
        int n = n0 + c * TPB;
        const float* p = preds + (size_t)(base + n) * 3;
        float px = p[0], py = p[1], pz = p[2];
        float qq = c1 * (px * px + py * py + pz * pz);
        px2[c] = (v2f){px, px}; py2[c] = (v2f){py, py}; pz2[c] = (v2f){pz, pz};
        qq2[c] = (v2f){qq, qq};
        RSa2[c] = (v2f){0.0f, 0.0f}; RRa2[c] = (v2f){0.0f, 0.0f};
    }
    __syncthreads();

#pragma unroll 4
    for (int h = 0; h < MTILE / 2; h++) {
        v4f L1 = s_la[h];
        v4f L2 = s_lb[h];
        v2f cc2 = s_cc2[h];
#pragma unroll
        for (int c = 0; c < CPT; c++) {
            v2f seed = pk_add(L2.zw, qq2[c]);
            v2f arg = pk_fma(L1.xy, px2[c],
                      pk_fma(L1.zw, py2[c],
                      pk_fma(L2.xy, pz2[c], seed)));
            v2f e2;
            e2.x = fast_exp2(arg.x);
            e2.y = fast_exp2(arg.y);
            v2f w2 = pk_mul(e2, cc2);
            RSa2[c] = pk_add(RSa2[c], w2);
            RRa2[c] = pk_fma(w2, arg, RRa2[c]);
        }
    }
#pragma unroll
    for (int c = 0; c < CPT; c++) {
        int idx = base + n0 + c * TPB;
        atomicAdd(&RSacc[idx], RSa2[c].x + RSa2[c].y);
        atomicAdd(&RRacc[idx], (RRa2[c].x + RRa2[c].y) * invc1);
    }
}

__global__ __launch_bounds__(TPB, 1) void k9f(
    const float* __restrict__ preds, const float* __restrict__ labels,
    const float* __restrict__ cur8, const float* __restrict__ RS8,
    const float* __restrict__ RR8, const float* __restrict__ cost9,
    float* __restrict__ out)
{
    __shared__ float tmp8[TPB / 64];
    int b = blockIdx.x, t = threadIdx.x;
    int base = b * NN;

    float cu9[K9C];
    float contrib = 0.0f, csum = 0.0f;
#pragma unroll
    for (int c = 0; c < K9C; c++) {
        int idx = base + t + c * TPB;
        float cup = cur8[idx];
        contrib = fmaf(cup, RR8[idx], contrib);
        float cu = fmaxf(cup * (1.0f - RS8[idx]), 0.0f);
        cu9[c] = cu; csum += cu;
    }
    float contribT = block_sum(contrib, t, tmp8);
    float Cb = block_sum(csum, t, tmp8);

    float A = 0.0f, Bs = 0.0f, Vx = 0.0f, Vy = 0.0f, Vz = 0.0f;
#pragma unroll
    for (int c = 0; c < K9C; c++) {
        int idx = base + t + c * TPB;
        const float* l = labels + (size_t)idx * 3;
        float lx = l[0], ly = l[1], lz = l[2];
        float cost = cost9[idx];
        float D1 = fmaf(cost, 2048.0f, EPSF);
        float S2 = cost * Cb / D1;
        float bw = fminf(cost / (S2 + EPSF), 1.0f);
        float cc = cost * bw / D1;
        A += cc;
        Bs = fmaf(cc, lx * lx + ly * ly + lz * lz, Bs);
        Vx = fmaf(cc, lx, Vx); Vy = fmaf(cc, ly, Vy); Vz = fmaf(cc, lz, Vz);
    }
    float At  = block_sum(A, t, tmp8);
    float Bt  = block_sum(Bs, t, tmp8);
    float Vxt = block_sum(Vx, t, tmp8);
    float Vyt = block_sum(Vy, t, tmp8);
    float Vzt = block_sum(Vz, t, tmp8);

    float acc = 0.0f;
#pragma unroll
    for (int c = 0; c < K9C; c++) {
        int idx = base + t + c * TPB;
        const float* p = preds + (size_t)idx * 3;
        float x = p[0], y = p[1], z = p[2];
        float pn = x * x + y * y + z * z;
        float rr = fmaf(At, pn, Bt) - 2.0f * (x * Vxt + y * Vyt + z * Vzt);
        acc = fmaf(cu9[c], rr, acc);
    }
    float accT = block_sum(acc, t, tmp8);
    if (t == 0) atomicAdd(out, contribT + accT);
}

extern "C" void kernel_launch(void* const* d_in, const int* in_sizes, int n_in,
                              void* d_out, int out_size, void* d_ws, size_t ws_size,
                              hipStream_t stream) {
    const float* preds  = (const float*)d_in[0];
    const float* labels = (const float*)d_in[1];
    float* out = (float*)d_out;
    float* ws  = (float*)d_ws;

    // Coop feasibility (deterministic per process -> same work every call).
    int nb = 0;
    hipError_t qrc = hipOccupancyMaxActiveBlocksPerMultiprocessor(
        &nb, (const void*)mega, TPB, 0);
    bool coop = (qrc == hipSuccess) && (nb * 256 >= MGRID);
    if (coop) {
        void* args[4] = {(void*)&preds, (void*)&labels, (void*)&out, (void*)&ws};
        hipError_t rc = hipLaunchCooperativeKernel((const void*)mega, dim3(MGRID),
                                                   dim3(TPB), args, 0, stream);
        if (rc != hipSuccess) coop = false;
    }
    if (!coop) {
        // R2-proven multi-kernel pk path
        float* S[2]     = {ws + 0 * BN, ws + 2 * BN};
        float* T[2]     = {ws + 1 * BN, ws + 3 * BN};
        float* RS[2]    = {ws + 4 * BN, ws + 6 * BN};
        float* RR[2]    = {ws + 5 * BN, ws + 7 * BN};
        float* curb[2]  = {ws + 8 * BN, ws + 9 * BN};
        float* costb[2] = {ws + 10 * BN, ws + 11 * BN};

        hipMemsetAsync(d_out, 0, sizeof(float), stream);
        hipMemsetAsync(ws, 0, (size_t)2 * BN * sizeof(float), stream);

        static const float efs[9] = {-16384.0f, -4096.0f, -1024.0f, -256.0f,
                                     -64.0f, -16.0f, -4.0f, -1.0f, -0.25f};
        const float log2e = 1.44269504088896f;
        for (int k = 0; k < 9; k++) {
            float c1 = efs[k] * log2e;
            float invc1 = 1.0f / c1;
            int pk = k & 1, pp = (k + 1) & 1;
            passAf<<<MGRID, TPB, 0, stream>>>(preds, labels,
                curb[pp], curb[pk], RS[pp], RR[pp], RS[pk], RR[pk],
                S[pk], T[pk], out, c1, k);
            passBf<<<MGRID, TPB, 0, stream>>>(preds, labels,
                S[pk], T[pk], costb[pk], costb[pp], S[pp], T[pp],
                RS[pk], RR[pk], c1, invc1, k);
        }
        k9f<<<BB, TPB, 0, stream>>>(preds, labels, curb[0], RS[0], RR[0],
                                    costb[1], out);
    }
}